// Round 2
// baseline (5607.657 us; speedup 1.0000x reference)
//
#include <hip/hip_runtime.h>

// ---------------------------------------------------------------------------
// 2-layer LSTM (B=256,T=512,H=512,DIN=64) + FC, persistent-kernel wavefront.
// R11: shrink the recurrence cycle (order change, not protocol change).
//  R10 evidence: fast flags + no-wbl2 gained only 1.6us/step -> detect/publish
//  were not dominant; the ~9us residue is the rest of the per-step chain.
//  Changes vs R10 (sync protocol byte-identical):
//   1. Per-step GEMM split: slack phase (L1: h0[s] 16 KC; L0: x 2 KC) runs
//      BEFORE the own-edge detect; only the own-dependent 16 KC + exchange +
//      cell + store + publish remain inside the recurrence cycle.
//   2. h1 stores agent-scope (L2 write-back; only same-XCD steady-state
//      readers + final-FC release flush) -> store drain ~300cyc, not LLC RTT.
//      h0 stays system-scope (cross-XCD L1 consumers need LLC truth).
//   3. Own-phase A-loads fully preloaded to registers (static unroll,
//      32 dwordx4 in flight) - VGPRs are free at 1 block/CU.
//  Correctness: inv-rotation guarantees same-XCD dirty-L2 lines are served
//  fresh post-inv; needRel fallback (self-test) unchanged; all cross-XCD
//  edges remain on LLC RMW counters.
// fp16 MFMA (16x16x32), fp32 accum, c-state in registers.
// ---------------------------------------------------------------------------

typedef _Float16 f16;
typedef _Float16 f16x8 __attribute__((ext_vector_type(8)));
typedef float    f32x4 __attribute__((ext_vector_type(4)));

constexpr int NB   = 256;   // batch
constexpr int NT   = 512;   // time steps
constexpr int NH   = 512;   // hidden
constexpr int NDIN = 64;    // input dim

constexpr int L0_KC = 18;   // K chunks of 32: 64(x) + 512(h0) = 576
constexpr int L1_KC = 32;   // 512(h0) + 512(h1) = 1024
constexpr int L0_IMG_HALVES = 4 * L0_KC * 64 * 8;  // 36864 f16 = 73728 B per htile
constexpr int L1_IMG_HALVES = 4 * L1_KC * 64 * 8;  // 65536 f16 = 131072 B per htile

constexpr int RING = 8;     // ring depth (address rotation period)

// ws layout (bytes), all 256-aligned
constexpr size_t BAR_OFF   = 0;                        // cnt[slot][group]: 64 lines * 128 B
constexpr size_t AUX_OFF   = 8192;                     // handshake/self-test lines (4 KB)
constexpr size_t BIAS0_OFF = 16384;                    // 2048 f32
constexpr size_t BIAS1_OFF = 24576;                    // 2048 f32
constexpr size_t FLAG_OFF  = 32768;                    // 256 blocks * 128 B (word0=step, word1=xcd id)
constexpr size_t H0R_OFF   = 65536;                    // [8][256][512] f16 = 2 MB
constexpr size_t H1R_OFF   = H0R_OFF + (size_t)RING * NB * NH * 2;   // + 2MB
constexpr size_t W0I_OFF   = H1R_OFF + (size_t)RING * NB * NH * 2;   // + 2MB
constexpr size_t W1I_OFF   = W0I_OFF + 2359296;        // 32 htiles * 73728 B
constexpr size_t WS_NEED   = W1I_OFF + 4194304;        // ~10.8 MB

// ---------------------------------------------------------------------------
// Prep: swizzle weights (fp32 -> fp16) into MFMA B-fragment order.
// B-frag layout (16x16x32): lane L holds B[k = (L>>4)*8 + j][n = L&15], j=0..7
// Image element order: [htile][nf(=gate)][kc][lane][8 halves]
// ---------------------------------------------------------------------------
__global__ void prep_weights(const float* __restrict__ Wih0, const float* __restrict__ Whh0,
                             const float* __restrict__ Wih1, const float* __restrict__ Whh1,
                             char* __restrict__ ws) {
    int idx = blockIdx.x * 256 + threadIdx.x;
    const int L0_CH = 32 * 4 * L0_KC * 64;   // 147456
    const int L1_CH = 32 * 4 * L1_KC * 64;   // 262144
    if (idx < L0_CH) {
        int lam = idx & 63;
        int kc  = (idx >> 6) % L0_KC;
        int nf  = ((idx >> 6) / L0_KC) & 3;
        int ht  = idx / (64 * L0_KC * 4);
        int g   = nf * NH + ht * 16 + (lam & 15);   // gate row in [0,2048)
        int kb  = kc * 32 + (lam >> 4) * 8;
        f16x8 v;
#pragma unroll
        for (int j = 0; j < 8; ++j) {
            int k = kb + j;
            float val = (k < NDIN) ? Wih0[(size_t)g * NDIN + k]
                                   : Whh0[(size_t)g * NH + (k - NDIN)];
            v[j] = (f16)val;
        }
        f16* dst = (f16*)(ws + W0I_OFF) + (size_t)ht * L0_IMG_HALVES
                 + ((size_t)(nf * L0_KC + kc) * 64 + lam) * 8;
        *(f16x8*)dst = v;
    } else if (idx < L0_CH + L1_CH) {
        int i2  = idx - L0_CH;
        int lam = i2 & 63;
        int kc  = (i2 >> 6) % L1_KC;
        int nf  = ((i2 >> 6) / L1_KC) & 3;
        int ht  = i2 / (64 * L1_KC * 4);
        int g   = nf * NH + ht * 16 + (lam & 15);
        int kb  = kc * 32 + (lam >> 4) * 8;
        f16x8 v;
#pragma unroll
        for (int j = 0; j < 8; ++j) {
            int k = kb + j;
            float val = (k < NH) ? Wih1[(size_t)g * NH + k]
                                 : Whh1[(size_t)g * NH + (k - NH)];
            v[j] = (f16)val;
        }
        f16* dst = (f16*)(ws + W1I_OFF) + (size_t)ht * L1_IMG_HALVES
                 + ((size_t)(nf * L1_KC + kc) * 64 + lam) * 8;
        *(f16x8*)dst = v;
    }
}

// bias sums + zero sync areas (BAR+AUX, FLAG) + zero both h rings (4 MB)
__global__ void prep_state(const float* __restrict__ bih0, const float* __restrict__ bhh0,
                           const float* __restrict__ bih1, const float* __restrict__ bhh1,
                           char* __restrict__ ws) {
    int idx = blockIdx.x * 256 + threadIdx.x;
    const int RINGU4 = (int)((size_t)2 * RING * NB * NH * 2 / 16);   // 262144
    if (idx < 2048) {
        ((float*)(ws + BIAS0_OFF))[idx] = bih0[idx] + bhh0[idx];
    } else if (idx < 4096) {
        int i = idx - 2048;
        ((float*)(ws + BIAS1_OFF))[i] = bih1[i] + bhh1[i];
    } else {
        int c = idx - 4096;
        uint4 z; z.x = z.y = z.z = z.w = 0u;
        if (c < 768) {                                  // BAR (8KB) + AUX (4KB)
            ((uint4*)(ws + BAR_OFF))[c] = z;
        } else if (c < 768 + 2048) {                    // FLAG 32KB
            ((uint4*)(ws + FLAG_OFF))[c - 768] = z;
        } else if (c < 768 + 2048 + RINGU4) {           // h0 + h1 rings contiguous
            ((uint4*)(ws + H0R_OFF))[c - 2816] = z;
        }
    }
}

// ---------------------------------------------------------------------------
// Persistent kernel helpers
// ---------------------------------------------------------------------------
__device__ __forceinline__ float sigf(float x) { return 1.f / (1.f + __expf(-x)); }
__device__ __forceinline__ float tanhx(float x) { float e = __expf(2.f * x); return 1.f - 2.f / (e + 1.f); }

// h stores. SYS=true: system scope (LLC write-through; cross-XCD consumers).
// SYS=false: agent scope (dirty in own L2; same-XCD consumers read it fresh
// post-inv; final FC correctness via the end-of-loop RELEASE flush).
template <bool SYS>
__device__ __forceinline__ void h_store(f16* p, float v) {
    unsigned short u = __builtin_bit_cast(unsigned short, (f16)v);
    __hip_atomic_store((unsigned short*)p, u, __ATOMIC_RELAXED,
                       SYS ? __HIP_MEMORY_SCOPE_SYSTEM : __HIP_MEMORY_SCOPE_AGENT);
}

// RMW poll: executes at the LLC (agent-scope atomicity) -> never stale.
// (Used on slack edges and as the E1 fallback.)
template <int SLP>
__device__ __forceinline__ void spin_cnt(unsigned* p, unsigned tgt) {
    while (__hip_atomic_fetch_add(p, 0u, __ATOMIC_RELAXED, __HIP_MEMORY_SCOPE_AGENT) < tgt)
        __builtin_amdgcn_s_sleep(SLP);
}

#define MFMA16(a, b, c) __builtin_amdgcn_mfma_f32_16x16x32_f16((a), (b), (c), 0, 0, 0)

__global__ __launch_bounds__(256, 1) void lstm_persist(char* __restrict__ ws,
                                                       const float* __restrict__ xin,
                                                       const float* __restrict__ fcW,
                                                       const float* __restrict__ fcb,
                                                       float* __restrict__ out) {
    extern __shared__ __align__(16) char smem[];
    f16*   sW   = (f16*)smem;                 // W image: up to 128 KB
    float* exch = (float*)(smem + 131072);    // 8 KB g/o exchange

    const int tid  = threadIdx.x;
    const int lam  = tid & 63;
    const int w    = tid >> 6;
    const int mh   = w & 1;          // M half (rows b0+mh*32 .. +31)
    const int nh   = w >> 1;         // N half: 0 -> gates i,f ; 1 -> gates g,o
    const int col  = lam & 15;
    const int quad = lam >> 4;

    const int bid   = blockIdx.x;
    const int gid   = bid & 7;               // group (XCD-aligned heuristic)
    const int layer = gid >> 2;              // 0..1
    const int b0    = (gid & 3) * 64;        // 4 B-tiles of 64
    const int ht    = bid >> 3;              // 32 H-tiles of 16
    const int h0c   = ht * 16;
    const int KCx   = layer ? L1_KC : L0_KC;

    // cnt line for (group g, ring slot k): one 128B line each
    auto cntp = [&](int g, int slot) -> unsigned* {
        return (unsigned*)(ws + BAR_OFF + (size_t)(slot * 8 + g) * 128);
    };
    unsigned* flags = (unsigned*)(ws + FLAG_OFF);         // 128B line per block
    unsigned* hsk   = (unsigned*)(ws + AUX_OFF);          // startup counter
    unsigned* trdy  = (unsigned*)(ws + AUX_OFF + 128);    // self-test ready
    unsigned* modep = (unsigned*)(ws + AUX_OFF + 256);    // bit1=done, bit0=need_release
    unsigned* finp  = (unsigned*)(ws + AUX_OFF + 384);    // final FC counter
    unsigned* tpat  = (unsigned*)(ws + AUX_OFF + 1024);   // test pattern, 16 words spread over 64B strides

    // ---- startup: XCD-id handshake + write-through self-test (tid 0) ----
    if (tid == 0) {
        unsigned myxid = (unsigned)__builtin_amdgcn_s_getreg((31 << 11) | (0 << 6) | 20) & 0xFu; // HW_REG_XCC_ID
        flags[(size_t)bid * 32 + 1] = myxid;
        __hip_atomic_fetch_add(hsk, 1u, __ATOMIC_RELEASE, __HIP_MEMORY_SCOPE_AGENT);  // flushes xid
        while (__hip_atomic_fetch_add(hsk, 0u, __ATOMIC_RELAXED, __HIP_MEMORY_SCOPE_AGENT) < 256u)
            __builtin_amdgcn_s_sleep(8);
        (void)__hip_atomic_load(hsk, __ATOMIC_ACQUIRE, __HIP_MEMORY_SCOPE_AGENT);     // inv -> fresh table
        unsigned fast = 1u;
        for (int i = 0; i < 32; ++i)
            if (flags[(size_t)(i * 8 + gid) * 32 + 1] != myxid) fast = 0u;
        int chk = 1;
        for (int i = 1; i < 256; ++i)
            if (flags[(size_t)i * 32 + 1] != flags[1]) { chk = i; break; }
        if (bid == 0) {
            for (int i = 0; i < 16; ++i)
                __hip_atomic_store(tpat + i * 16, 0xC0FFEE00u + (unsigned)i,
                                   __ATOMIC_RELAXED, __HIP_MEMORY_SCOPE_SYSTEM);
            asm volatile("s_waitcnt vmcnt(0)" ::: "memory");
            __hip_atomic_fetch_add(trdy, 1u, __ATOMIC_RELAXED, __HIP_MEMORY_SCOPE_AGENT);
        }
        if (bid == chk) {
            while (__hip_atomic_fetch_add(trdy, 0u, __ATOMIC_RELAXED, __HIP_MEMORY_SCOPE_AGENT) < 1u)
                __builtin_amdgcn_s_sleep(8);
            unsigned ok = 1u;   // ANY mismatch -> safe (release) mode
            for (int i = 0; i < 16; ++i)
                if (__hip_atomic_load(tpat + i * 16, __ATOMIC_RELAXED, __HIP_MEMORY_SCOPE_SYSTEM)
                    != 0xC0FFEE00u + (unsigned)i) ok = 0u;
            __hip_atomic_fetch_add(modep, 2u | (ok ? 0u : 1u), __ATOMIC_RELAXED, __HIP_MEMORY_SCOPE_AGENT);
        }
        unsigned mv; int spins = 0;
        while ((mv = __hip_atomic_fetch_add(modep, 0u, __ATOMIC_RELAXED, __HIP_MEMORY_SCOPE_AGENT)) < 2u) {
            __builtin_amdgcn_s_sleep(16);
            if (++spins > (1 << 22)) { mv = 3u; break; }   // timeout -> safe mode
        }
        ((unsigned*)exch)[0] = fast;
        ((unsigned*)exch)[1] = mv & 1u;
    }
    __syncthreads();
    unsigned       fastE1  = ((unsigned*)exch)[0];   // wave0's copy may later flip to 0
    const unsigned needRel = ((unsigned*)exch)[1];
    __syncthreads();

    f16* h0ring = (f16*)(ws + H0R_OFF);
    f16* h1ring = (f16*)(ws + H1R_OFF);
    const float* bias = (const float*)(ws + (layer ? BIAS1_OFF : BIAS0_OFF));
    const f16*   wimg = (const f16*)(ws + (layer ? W1I_OFF : W0I_OFF))
                      + (size_t)ht * (layer ? L1_IMG_HALVES : L0_IMG_HALVES);

    // Stage this block's W slice into LDS once (lives for all 512 steps).
    {
        const int n16 = KCx * 4 * 64;        // uint4 chunks
        const uint4* src = (const uint4*)wimg;
        uint4* dst = (uint4*)sW;
        for (int i = tid; i < n16; i += 256) dst[i] = src[i];
    }
    __syncthreads();

    const float bi_i = bias[0 * NH + h0c + col];
    const float bi_f = bias[1 * NH + h0c + col];
    const float bi_g = bias[2 * NH + h0c + col];
    const float bi_o = bias[3 * NH + h0c + col];

    float cst[2][4];                          // c state (nh==0 waves)
#pragma unroll
    for (int a = 0; a < 2; ++a)
#pragma unroll
        for (int r = 0; r < 4; ++r) cst[a][r] = 0.f;

    const f16x8* sBf = (const f16x8*)sW;
    const int nf0 = nh * 2, nf1 = nh * 2 + 1;
    const int rA0 = b0 + mh * 32 + col;       // A-row for m-frag 0; +16 for frag 1

    for (int s = 0; s < NT; ++s) {
        const unsigned us = (unsigned)s;

        // ================= SLACK phase (outside the recurrence cycle) =====
        // slack polls (single-lane RMW at LLC; big slack hides their latency)
        if (layer == 0) {
            // WAR (slack 8): L1 partner done step s-8 (we overwrite h0 slot s&7)
            if (tid == 64 && s >= RING)
                spin_cnt<8>(cntp(gid + 4, s & 7), 32u * (us >> 3));
        } else {
            // L0 partner done step s (h0[s] ready; L0 leads -> usually instant)
            if (tid == 64)
                spin_cnt<4>(cntp(gid - 4, s & 7), 32u * ((us >> 3) + 1));
        }
        __syncthreads();   // B1: slack data ready / WAR clear

        f32x4 acc00 = {0.f,0.f,0.f,0.f}, acc01 = {0.f,0.f,0.f,0.f};
        f32x4 acc10 = {0.f,0.f,0.f,0.f}, acc11 = {0.f,0.f,0.f,0.f};

        if (layer == 0) {
            // x part: kc 0..1 (no dependency at all)
            auto ldX = [&](int row, int kc) -> f16x8 {
                const float* xr = xin + (size_t)row * (NT * NDIN) + (size_t)s * NDIN + kc * 32 + quad * 8;
                float4 f0 = *(const float4*)xr;
                float4 f1 = *(const float4*)(xr + 4);
                f16x8 v;
                v[0] = (f16)f0.x; v[1] = (f16)f0.y; v[2] = (f16)f0.z; v[3] = (f16)f0.w;
                v[4] = (f16)f1.x; v[5] = (f16)f1.y; v[6] = (f16)f1.z; v[7] = (f16)f1.w;
                return v;
            };
#pragma unroll
            for (int j = 0; j < 2; ++j) {
                f16x8 a0 = ldX(rA0, j);
                f16x8 a1 = ldX(rA0 + 16, j);
                f16x8 w0 = sBf[(nf0 * L0_KC + j) * 64 + lam];
                f16x8 w1 = sBf[(nf1 * L0_KC + j) * 64 + lam];
                acc00 = MFMA16(a0, w0, acc00);
                acc01 = MFMA16(a0, w1, acc01);
                acc10 = MFMA16(a1, w0, acc10);
                acc11 = MFMA16(a1, w1, acc11);
            }
        } else {
            // h0[s] part: kc 0..15 (depends only on L0, which leads)
            const f16* hp0 = h0ring + (size_t)(s & 7) * (NB * NH);
            f16x8 a0v[16], a1v[16];
#pragma unroll
            for (int j = 0; j < 16; ++j) {
                a0v[j] = *(const f16x8*)(hp0 + (size_t)rA0 * NH + j * 32 + quad * 8);
                a1v[j] = *(const f16x8*)(hp0 + (size_t)(rA0 + 16) * NH + j * 32 + quad * 8);
            }
#pragma unroll
            for (int j = 0; j < 16; ++j) {
                f16x8 w0 = sBf[(nf0 * L1_KC + j) * 64 + lam];
                f16x8 w1 = sBf[(nf1 * L1_KC + j) * 64 + lam];
                acc00 = MFMA16(a0v[j], w0, acc00);
                acc01 = MFMA16(a0v[j], w1, acc01);
                acc10 = MFMA16(a1v[j], w0, acc10);
                acc11 = MFMA16(a1v[j], w1, acc11);
            }
        }

        // ================= CRITICAL cycle: detect own edge =================
        // Fast path: multi-lane sc0 poll of the group's 32 flag lines in the
        // shared XCD L2. Bounded spins -> permanent RMW fallback.
        if (s > 0 && w == 0) {
            if (fastE1) {
                unsigned* fp = flags + (size_t)((lam & 31) * 8 + gid) * 32;
                int tries = 0;
                for (;;) {
                    unsigned v = __hip_atomic_load(fp, __ATOMIC_RELAXED, __HIP_MEMORY_SCOPE_AGENT);
                    if (__all((int)(v >= us))) break;
                    if (++tries > 4096) { fastE1 = 0u; break; }
                    __builtin_amdgcn_s_sleep(1);
                }
            }
            if (!fastE1 && tid == 0)
                spin_cnt<1>(cntp(gid, (s - 1) & 7), 32u * (((us - 1) >> 3) + 1));
        }
        __syncthreads();   // B2: own-layer h[s-1] visible

        // ---- own-dependent 16 KC: full register preload, then MFMA ----
        {
            const f16* hpo = (layer ? h1ring : h0ring) + (size_t)((s - 1) & 7) * (NB * NH);
            const int  wb  = layer ? 16 : 2;     // weight-image kc base
            f16x8 a0v[16], a1v[16];
#pragma unroll
            for (int j = 0; j < 16; ++j) {
                a0v[j] = *(const f16x8*)(hpo + (size_t)rA0 * NH + j * 32 + quad * 8);
                a1v[j] = *(const f16x8*)(hpo + (size_t)(rA0 + 16) * NH + j * 32 + quad * 8);
            }
#pragma unroll
            for (int j = 0; j < 16; ++j) {
                f16x8 w0 = sBf[(nf0 * KCx + wb + j) * 64 + lam];
                f16x8 w1 = sBf[(nf1 * KCx + wb + j) * 64 + lam];
                acc00 = MFMA16(a0v[j], w0, acc00);
                acc01 = MFMA16(a0v[j], w1, acc01);
                acc10 = MFMA16(a1v[j], w0, acc10);
                acc11 = MFMA16(a1v[j], w1, acc11);
            }
        }

        // g/o waves hand their accs to i/f waves; cell update is register-local there.
        if (nh == 1) {
            f32x4* e4 = (f32x4*)exch;
            e4[((mh * 2 + 0) * 2 + 0) * 64 + lam] = acc00;   // mf0, gate g
            e4[((mh * 2 + 0) * 2 + 1) * 64 + lam] = acc01;   // mf0, gate o
            e4[((mh * 2 + 1) * 2 + 0) * 64 + lam] = acc10;   // mf1, gate g
            e4[((mh * 2 + 1) * 2 + 1) * 64 + lam] = acc11;   // mf1, gate o
        }
        __syncthreads();   // B3: all waves' A-loads consumed beyond this point

        // ---- staleness bound: one acquire-inv per block every RING steps,
        // phase-spread by ht, post-consumption (off the critical detect path).
        if (tid == 128 && ((s & 7) == (ht & 7)))
            (void)__hip_atomic_load((unsigned*)(ws + BAR_OFF), __ATOMIC_ACQUIRE, __HIP_MEMORY_SCOPE_AGENT);

        if (nh == 0) {
            const f32x4* e4 = (const f32x4*)exch;
            f32x4 gg0 = e4[((mh * 2 + 0) * 2 + 0) * 64 + lam];
            f32x4 oo0 = e4[((mh * 2 + 0) * 2 + 1) * 64 + lam];
            f32x4 gg1 = e4[((mh * 2 + 1) * 2 + 0) * 64 + lam];
            f32x4 oo1 = e4[((mh * 2 + 1) * 2 + 1) * 64 + lam];
            f16* hw = (layer ? h1ring : h0ring) + (size_t)(s & 7) * (NB * NH);
#pragma unroll
            for (int mf = 0; mf < 2; ++mf) {
                f32x4 ai = mf ? acc10 : acc00;
                f32x4 af = mf ? acc11 : acc01;
                f32x4 ag = mf ? gg1 : gg0;
                f32x4 ao = mf ? oo1 : oo0;
#pragma unroll
                for (int r = 0; r < 4; ++r) {
                    float iv = ai[r] + bi_i;
                    float fv = af[r] + bi_f;
                    float gv = ag[r] + bi_g;
                    float ov = ao[r] + bi_o;
                    float cc = sigf(fv) * cst[mf][r] + sigf(iv) * tanhx(gv);
                    cst[mf][r] = cc;
                    float hh = sigf(ov) * tanhx(cc);
                    // C/D layout: row = quad*4 + r, col = lane&15
                    f16* dst = &hw[(size_t)(b0 + mh * 32 + mf * 16 + quad * 4 + r) * NH + h0c + col];
                    if (layer) h_store<false>(dst, hh);   // h1: agent (own-L2 dirty)
                    else       h_store<true >(dst, hh);   // h0: system (LLC truth)
                }
            }
        }

        // ---- publish: B4 drains all h-stores (vmcnt(0) before s_barrier ->
        // system stores complete AT the LLC, agent stores in own L2). Then
        // wave 3 (never a poller) posts flag (L2 fast path) + cnt RMW (LLC).
        // RELEASE only if the self-test found system stores don't write through.
        __syncthreads();   // B4
        if (tid == 192) {
            __hip_atomic_store(flags + (size_t)bid * 32, us + 1u,
                               __ATOMIC_RELAXED, __HIP_MEMORY_SCOPE_AGENT);
            if (needRel)
                __hip_atomic_fetch_add(cntp(gid, s & 7), 1u, __ATOMIC_RELEASE, __HIP_MEMORY_SCOPE_AGENT);
            else
                __hip_atomic_fetch_add(cntp(gid, s & 7), 1u, __ATOMIC_RELAXED, __HIP_MEMORY_SCOPE_AGENT);
        }
    }

    // L1 blocks: one final RELEASE publish (wbl2 flushes dirty agent-scope h1
    // to the LLC) so the FC reader is correct in every mode.
    if (layer == 1 && tid == 0)
        __hip_atomic_fetch_add(finp, 1u, __ATOMIC_RELEASE, __HIP_MEMORY_SCOPE_AGENT);

    // Final FC by block 0: all 128 L1 blocks must have finished step 511.
    if (bid == 0) {
        if (tid == 0) {
            while (__hip_atomic_fetch_add(finp, 0u, __ATOMIC_RELAXED, __HIP_MEMORY_SCOPE_AGENT) < 128u)
                __builtin_amdgcn_s_sleep(8);
            (void)__hip_atomic_load((unsigned*)(ws + BAR_OFF), __ATOMIC_ACQUIRE, __HIP_MEMORY_SCOPE_AGENT);
        }
        __syncthreads();
        const f16* hrow = h1ring + (size_t)7 * (NB * NH) + (size_t)tid * NH;  // slot 511&7 = 7
        float acc = fcb[0];
#pragma unroll 4
        for (int j = 0; j < NH; j += 8) {
            f16x8 hv = *(const f16x8*)(hrow + j);
#pragma unroll
            for (int e = 0; e < 8; ++e) acc += fcW[j + e] * (float)hv[e];
        }
        out[tid] = acc;
    }
}

// ---------------------------------------------------------------------------
extern "C" void kernel_launch(void* const* d_in, const int* in_sizes, int n_in,
                              void* d_out, int out_size, void* d_ws, size_t ws_size,
                              hipStream_t stream) {
    const float* x    = (const float*)d_in[0];
    const float* Wih0 = (const float*)d_in[1];
    const float* Whh0 = (const float*)d_in[2];
    const float* bih0 = (const float*)d_in[3];
    const float* bhh0 = (const float*)d_in[4];
    const float* Wih1 = (const float*)d_in[5];
    const float* Whh1 = (const float*)d_in[6];
    const float* bih1 = (const float*)d_in[7];
    const float* bhh1 = (const float*)d_in[8];
    const float* fcW  = (const float*)d_in[9];
    const float* fcb  = (const float*)d_in[10];
    char*  ws  = (char*)d_ws;
    float* out = (float*)d_out;

    if (ws_size < WS_NEED) {  // deterministic failure instead of corruption
        hipMemsetAsync(d_out, 0, (size_t)out_size * sizeof(float), stream);
        return;
    }

    hipFuncSetAttribute(reinterpret_cast<const void*>(lstm_persist),
                        hipFuncAttributeMaxDynamicSharedMemorySize, 139264);

    prep_weights<<<1600, 256, 0, stream>>>(Wih0, Whh0, Wih1, Whh1, ws);
    prep_state<<<1100, 256, 0, stream>>>(bih0, bhh0, bih1, bhh1, ws);
    // 256 blocks, 139264 B dynamic LDS -> exactly 1 block/CU on 256 CUs
    lstm_persist<<<256, 256, 139264, stream>>>(ws, x, fcW, fcb, out);
}

// Round 3
// 5527.419 us; speedup vs baseline: 1.0145x; 1.0145x over previous
//
#include <hip/hip_runtime.h>

// ---------------------------------------------------------------------------
// 2-layer LSTM (B=256,T=512,H=512,DIN=64) + FC, persistent-kernel wavefront.
// R12: dedicated sync wave + LDS go-flags.
//  Evidence: R9/R10/R11 (three different sync protocols) all ~11us/step ->
//  no single edge latency dominates; the cost is the SUM of serialized
//  latency segments (poll -> barrier -> GEMM -> poll -> barrier -> ... ),
//  each exposing 0.3-1.5us because the polling waves are the compute waves.
//  Fix: 5th wave (block=320) does all inter-block polling CONCURRENTLY with
//  the compute waves' slack GEMM, posting monotonic go-counters in LDS.
//  Compute waves spin on LDS (~0.1us) instead of barriers; per-step barriers
//  drop 4 -> 2 (exchange order, store drain). Publish by the sync wave.
//  Dependency graph, poll targets, ring rotation, inv machinery, fallback
//  paths, store scopes: byte-identical to R11 (which passed).
// fp16 MFMA (16x16x32), fp32 accum, c-state in registers.
// ---------------------------------------------------------------------------

typedef _Float16 f16;
typedef _Float16 f16x8 __attribute__((ext_vector_type(8)));
typedef float    f32x4 __attribute__((ext_vector_type(4)));

constexpr int NB   = 256;   // batch
constexpr int NT   = 512;   // time steps
constexpr int NH   = 512;   // hidden
constexpr int NDIN = 64;    // input dim

constexpr int L0_KC = 18;   // K chunks of 32: 64(x) + 512(h0) = 576
constexpr int L1_KC = 32;   // 512(h0) + 512(h1) = 1024
constexpr int L0_IMG_HALVES = 4 * L0_KC * 64 * 8;  // 36864 f16 = 73728 B per htile
constexpr int L1_IMG_HALVES = 4 * L1_KC * 64 * 8;  // 65536 f16 = 131072 B per htile

constexpr int RING = 8;     // ring depth (address rotation period)

// ws layout (bytes), all 256-aligned
constexpr size_t BAR_OFF   = 0;                        // cnt[slot][group]: 64 lines * 128 B
constexpr size_t AUX_OFF   = 8192;                     // handshake/self-test lines (4 KB)
constexpr size_t BIAS0_OFF = 16384;                    // 2048 f32
constexpr size_t BIAS1_OFF = 24576;                    // 2048 f32
constexpr size_t FLAG_OFF  = 32768;                    // 256 blocks * 128 B (word0=step, word1=xcd id)
constexpr size_t H0R_OFF   = 65536;                    // [8][256][512] f16 = 2 MB
constexpr size_t H1R_OFF   = H0R_OFF + (size_t)RING * NB * NH * 2;   // + 2MB
constexpr size_t W0I_OFF   = H1R_OFF + (size_t)RING * NB * NH * 2;   // + 2MB
constexpr size_t W1I_OFF   = W0I_OFF + 2359296;        // 32 htiles * 73728 B
constexpr size_t WS_NEED   = W1I_OFF + 4194304;        // ~10.8 MB

// LDS layout
constexpr int LDS_EXCH = 131072;    // f32x4 exchange (8 KB)
constexpr int LDS_GO   = 139264;    // 2 go words
constexpr int LDS_SIZE = 139520;

// ---------------------------------------------------------------------------
// Prep: swizzle weights (fp32 -> fp16) into MFMA B-fragment order.
// B-frag layout (16x16x32): lane L holds B[k = (L>>4)*8 + j][n = L&15], j=0..7
// Image element order: [htile][nf(=gate)][kc][lane][8 halves]
// ---------------------------------------------------------------------------
__global__ void prep_weights(const float* __restrict__ Wih0, const float* __restrict__ Whh0,
                             const float* __restrict__ Wih1, const float* __restrict__ Whh1,
                             char* __restrict__ ws) {
    int idx = blockIdx.x * 256 + threadIdx.x;
    const int L0_CH = 32 * 4 * L0_KC * 64;   // 147456
    const int L1_CH = 32 * 4 * L1_KC * 64;   // 262144
    if (idx < L0_CH) {
        int lam = idx & 63;
        int kc  = (idx >> 6) % L0_KC;
        int nf  = ((idx >> 6) / L0_KC) & 3;
        int ht  = idx / (64 * L0_KC * 4);
        int g   = nf * NH + ht * 16 + (lam & 15);   // gate row in [0,2048)
        int kb  = kc * 32 + (lam >> 4) * 8;
        f16x8 v;
#pragma unroll
        for (int j = 0; j < 8; ++j) {
            int k = kb + j;
            float val = (k < NDIN) ? Wih0[(size_t)g * NDIN + k]
                                   : Whh0[(size_t)g * NH + (k - NDIN)];
            v[j] = (f16)val;
        }
        f16* dst = (f16*)(ws + W0I_OFF) + (size_t)ht * L0_IMG_HALVES
                 + ((size_t)(nf * L0_KC + kc) * 64 + lam) * 8;
        *(f16x8*)dst = v;
    } else if (idx < L0_CH + L1_CH) {
        int i2  = idx - L0_CH;
        int lam = i2 & 63;
        int kc  = (i2 >> 6) % L1_KC;
        int nf  = ((i2 >> 6) / L1_KC) & 3;
        int ht  = i2 / (64 * L1_KC * 4);
        int g   = nf * NH + ht * 16 + (lam & 15);
        int kb  = kc * 32 + (lam >> 4) * 8;
        f16x8 v;
#pragma unroll
        for (int j = 0; j < 8; ++j) {
            int k = kb + j;
            float val = (k < NH) ? Wih1[(size_t)g * NH + k]
                                 : Whh1[(size_t)g * NH + (k - NH)];
            v[j] = (f16)val;
        }
        f16* dst = (f16*)(ws + W1I_OFF) + (size_t)ht * L1_IMG_HALVES
                 + ((size_t)(nf * L1_KC + kc) * 64 + lam) * 8;
        *(f16x8*)dst = v;
    }
}

// bias sums + zero sync areas (BAR+AUX, FLAG) + zero both h rings (4 MB)
__global__ void prep_state(const float* __restrict__ bih0, const float* __restrict__ bhh0,
                           const float* __restrict__ bih1, const float* __restrict__ bhh1,
                           char* __restrict__ ws) {
    int idx = blockIdx.x * 256 + threadIdx.x;
    const int RINGU4 = (int)((size_t)2 * RING * NB * NH * 2 / 16);   // 262144
    if (idx < 2048) {
        ((float*)(ws + BIAS0_OFF))[idx] = bih0[idx] + bhh0[idx];
    } else if (idx < 4096) {
        int i = idx - 2048;
        ((float*)(ws + BIAS1_OFF))[i] = bih1[i] + bhh1[i];
    } else {
        int c = idx - 4096;
        uint4 z; z.x = z.y = z.z = z.w = 0u;
        if (c < 768) {                                  // BAR (8KB) + AUX (4KB)
            ((uint4*)(ws + BAR_OFF))[c] = z;
        } else if (c < 768 + 2048) {                    // FLAG 32KB
            ((uint4*)(ws + FLAG_OFF))[c - 768] = z;
        } else if (c < 768 + 2048 + RINGU4) {           // h0 + h1 rings contiguous
            ((uint4*)(ws + H0R_OFF))[c - 2816] = z;
        }
    }
}

// ---------------------------------------------------------------------------
// Persistent kernel helpers
// ---------------------------------------------------------------------------
__device__ __forceinline__ float sigf(float x) { return 1.f / (1.f + __expf(-x)); }
__device__ __forceinline__ float tanhx(float x) { float e = __expf(2.f * x); return 1.f - 2.f / (e + 1.f); }

// h stores. SYS=true: system scope (LLC write-through; cross-XCD consumers).
// SYS=false: agent scope (dirty in own L2; same-XCD consumers read it fresh
// post-inv; final FC correctness via the end-of-loop RELEASE flush).
template <bool SYS>
__device__ __forceinline__ void h_store(f16* p, float v) {
    unsigned short u = __builtin_bit_cast(unsigned short, (f16)v);
    __hip_atomic_store((unsigned short*)p, u, __ATOMIC_RELAXED,
                       SYS ? __HIP_MEMORY_SCOPE_SYSTEM : __HIP_MEMORY_SCOPE_AGENT);
}

// RMW poll: executes at the LLC (agent-scope atomicity) -> never stale.
template <int SLP>
__device__ __forceinline__ void spin_cnt(unsigned* p, unsigned tgt) {
    while (__hip_atomic_fetch_add(p, 0u, __ATOMIC_RELAXED, __HIP_MEMORY_SCOPE_AGENT) < tgt)
        __builtin_amdgcn_s_sleep(SLP);
}

#define MFMA16(a, b, c) __builtin_amdgcn_mfma_f32_16x16x32_f16((a), (b), (c), 0, 0, 0)

__global__ __launch_bounds__(320, 1) void lstm_persist(char* __restrict__ ws,
                                                       const float* __restrict__ xin,
                                                       const float* __restrict__ fcW,
                                                       const float* __restrict__ fcb,
                                                       float* __restrict__ out) {
    extern __shared__ __align__(16) char smem[];
    f16*   sW   = (f16*)smem;                      // W image: up to 128 KB
    float* exch = (float*)(smem + LDS_EXCH);       // 8 KB g/o exchange
    unsigned* go = (unsigned*)(smem + LDS_GO);     // go[0]=slack, go[1]=own

    const int tid  = threadIdx.x;
    const int lam  = tid & 63;
    const int w    = tid >> 6;       // 0..3 compute, 4 sync
    const int mh   = w & 1;          // M half (rows b0+mh*32 .. +31)
    const int nh   = (w >> 1) & 1;   // N half: 0 -> gates i,f ; 1 -> gates g,o
    const int col  = lam & 15;
    const int quad = lam >> 4;

    const int bid   = blockIdx.x;
    const int gid   = bid & 7;               // group (XCD-aligned heuristic)
    const int layer = gid >> 2;              // 0..1
    const int b0    = (gid & 3) * 64;        // 4 B-tiles of 64
    const int ht    = bid >> 3;              // 32 H-tiles of 16
    const int h0c   = ht * 16;
    const int KCx   = layer ? L1_KC : L0_KC;

    // cnt line for (group g, ring slot k): one 128B line each
    auto cntp = [&](int g, int slot) -> unsigned* {
        return (unsigned*)(ws + BAR_OFF + (size_t)(slot * 8 + g) * 128);
    };
    unsigned* flags = (unsigned*)(ws + FLAG_OFF);         // 128B line per block
    unsigned* hsk   = (unsigned*)(ws + AUX_OFF);          // startup counter
    unsigned* trdy  = (unsigned*)(ws + AUX_OFF + 128);    // self-test ready
    unsigned* modep = (unsigned*)(ws + AUX_OFF + 256);    // bit1=done, bit0=need_release
    unsigned* finp  = (unsigned*)(ws + AUX_OFF + 384);    // final FC counter
    unsigned* tpat  = (unsigned*)(ws + AUX_OFF + 1024);   // test pattern

    // ---- startup: XCD-id handshake + write-through self-test (tid 0) ----
    if (tid == 0) {
        go[0] = 0u; go[1] = 0u;
        unsigned myxid = (unsigned)__builtin_amdgcn_s_getreg((31 << 11) | (0 << 6) | 20) & 0xFu; // HW_REG_XCC_ID
        flags[(size_t)bid * 32 + 1] = myxid;
        __hip_atomic_fetch_add(hsk, 1u, __ATOMIC_RELEASE, __HIP_MEMORY_SCOPE_AGENT);  // flushes xid
        while (__hip_atomic_fetch_add(hsk, 0u, __ATOMIC_RELAXED, __HIP_MEMORY_SCOPE_AGENT) < 256u)
            __builtin_amdgcn_s_sleep(8);
        (void)__hip_atomic_load(hsk, __ATOMIC_ACQUIRE, __HIP_MEMORY_SCOPE_AGENT);     // inv -> fresh table
        unsigned fast = 1u;
        for (int i = 0; i < 32; ++i)
            if (flags[(size_t)(i * 8 + gid) * 32 + 1] != myxid) fast = 0u;
        int chk = 1;
        for (int i = 1; i < 256; ++i)
            if (flags[(size_t)i * 32 + 1] != flags[1]) { chk = i; break; }
        if (bid == 0) {
            for (int i = 0; i < 16; ++i)
                __hip_atomic_store(tpat + i * 16, 0xC0FFEE00u + (unsigned)i,
                                   __ATOMIC_RELAXED, __HIP_MEMORY_SCOPE_SYSTEM);
            asm volatile("s_waitcnt vmcnt(0)" ::: "memory");
            __hip_atomic_fetch_add(trdy, 1u, __ATOMIC_RELAXED, __HIP_MEMORY_SCOPE_AGENT);
        }
        if (bid == chk) {
            while (__hip_atomic_fetch_add(trdy, 0u, __ATOMIC_RELAXED, __HIP_MEMORY_SCOPE_AGENT) < 1u)
                __builtin_amdgcn_s_sleep(8);
            unsigned ok = 1u;   // ANY mismatch -> safe (release) mode
            for (int i = 0; i < 16; ++i)
                if (__hip_atomic_load(tpat + i * 16, __ATOMIC_RELAXED, __HIP_MEMORY_SCOPE_SYSTEM)
                    != 0xC0FFEE00u + (unsigned)i) ok = 0u;
            __hip_atomic_fetch_add(modep, 2u | (ok ? 0u : 1u), __ATOMIC_RELAXED, __HIP_MEMORY_SCOPE_AGENT);
        }
        unsigned mv; int spins = 0;
        while ((mv = __hip_atomic_fetch_add(modep, 0u, __ATOMIC_RELAXED, __HIP_MEMORY_SCOPE_AGENT)) < 2u) {
            __builtin_amdgcn_s_sleep(16);
            if (++spins > (1 << 22)) { mv = 3u; break; }   // timeout -> safe mode
        }
        ((unsigned*)exch)[0] = fast;
        ((unsigned*)exch)[1] = mv & 1u;
    }
    __syncthreads();
    unsigned       fastE1  = ((unsigned*)exch)[0];   // sync wave's copy may flip to 0
    const unsigned needRel = ((unsigned*)exch)[1];
    __syncthreads();

    f16* h0ring = (f16*)(ws + H0R_OFF);
    f16* h1ring = (f16*)(ws + H1R_OFF);
    const float* bias = (const float*)(ws + (layer ? BIAS1_OFF : BIAS0_OFF));
    const f16*   wimg = (const f16*)(ws + (layer ? W1I_OFF : W0I_OFF))
                      + (size_t)ht * (layer ? L1_IMG_HALVES : L0_IMG_HALVES);

    // Stage this block's W slice into LDS once (lives for all 512 steps).
    {
        const int n16 = KCx * 4 * 64;        // uint4 chunks
        const uint4* src = (const uint4*)wimg;
        uint4* dst = (uint4*)sW;
        for (int i = tid; i < n16; i += 320) dst[i] = src[i];
    }
    __syncthreads();

    const float bi_i = bias[0 * NH + h0c + col];
    const float bi_f = bias[1 * NH + h0c + col];
    const float bi_g = bias[2 * NH + h0c + col];
    const float bi_o = bias[3 * NH + h0c + col];

    float cst[2][4];                          // c state (nh==0 compute waves)
#pragma unroll
    for (int a = 0; a < 2; ++a)
#pragma unroll
        for (int r = 0; r < 4; ++r) cst[a][r] = 0.f;

    const f16x8* sBf = (const f16x8*)sW;
    const int nf0 = nh * 2, nf1 = nh * 2 + 1;
    const int rA0 = b0 + mh * 32 + col;       // A-row for m-frag 0; +16 for frag 1

    for (int s = 0; s < NT; ++s) {
        const unsigned us = (unsigned)s;

        f32x4 acc00 = {0.f,0.f,0.f,0.f}, acc01 = {0.f,0.f,0.f,0.f};
        f32x4 acc10 = {0.f,0.f,0.f,0.f}, acc11 = {0.f,0.f,0.f,0.f};

        if (w == 4) {
            // ======== SYNC WAVE: poll both edges while compute runs ========
            // slack edge (LLC RMW; real slack in steady state)
            if (lam == 0) {
                if (layer == 0) {
                    if (s >= RING)  // WAR: L1 partner done s-8 before we overwrite slot s&7
                        spin_cnt<8>(cntp(gid + 4, s & 7), 32u * (us >> 3));
                } else {
                    // L0 partner done step s (L0 leads -> usually instant)
                    spin_cnt<4>(cntp(gid - 4, s & 7), 32u * ((us >> 3) + 1));
                }
            }
            __hip_atomic_store(&go[0], us + 1u, __ATOMIC_RELAXED, __HIP_MEMORY_SCOPE_WORKGROUP);
            // own edge (critical): group done step s-1. Fast: 32-lane flag poll
            // in shared XCD L2; bounded spins -> permanent RMW fallback.
            if (s > 0) {
                if (fastE1) {
                    unsigned* fp = flags + (size_t)((lam & 31) * 8 + gid) * 32;
                    int tries = 0;
                    for (;;) {
                        unsigned v = __hip_atomic_load(fp, __ATOMIC_RELAXED, __HIP_MEMORY_SCOPE_AGENT);
                        if (__all((int)(v >= us))) break;
                        if (++tries > 4096) { fastE1 = 0u; break; }
                        __builtin_amdgcn_s_sleep(1);
                    }
                }
                if (!fastE1 && lam == 0)
                    spin_cnt<1>(cntp(gid, (s - 1) & 7), 32u * (((us - 1) >> 3) + 1));
            }
            __hip_atomic_store(&go[1], us + 1u, __ATOMIC_RELAXED, __HIP_MEMORY_SCOPE_WORKGROUP);
        } else {
            // ======== COMPUTE WAVES ========
            // ---- slack phase (gated by go[0]; no barrier) ----
            while (__hip_atomic_load(&go[0], __ATOMIC_RELAXED, __HIP_MEMORY_SCOPE_WORKGROUP) <= us)
                __builtin_amdgcn_s_sleep(1);

            if (layer == 0) {
                // x part: kc 0..1 (no dependency)
                auto ldX = [&](int row, int kc) -> f16x8 {
                    const float* xr = xin + (size_t)row * (NT * NDIN) + (size_t)s * NDIN + kc * 32 + quad * 8;
                    float4 f0 = *(const float4*)xr;
                    float4 f1 = *(const float4*)(xr + 4);
                    f16x8 v;
                    v[0] = (f16)f0.x; v[1] = (f16)f0.y; v[2] = (f16)f0.z; v[3] = (f16)f0.w;
                    v[4] = (f16)f1.x; v[5] = (f16)f1.y; v[6] = (f16)f1.z; v[7] = (f16)f1.w;
                    return v;
                };
#pragma unroll
                for (int j = 0; j < 2; ++j) {
                    f16x8 a0 = ldX(rA0, j);
                    f16x8 a1 = ldX(rA0 + 16, j);
                    f16x8 w0 = sBf[(nf0 * L0_KC + j) * 64 + lam];
                    f16x8 w1 = sBf[(nf1 * L0_KC + j) * 64 + lam];
                    acc00 = MFMA16(a0, w0, acc00);
                    acc01 = MFMA16(a0, w1, acc01);
                    acc10 = MFMA16(a1, w0, acc10);
                    acc11 = MFMA16(a1, w1, acc11);
                }
            } else {
                // h0[s] part: kc 0..15 (depends only on L0, which leads)
                const f16* hp0 = h0ring + (size_t)(s & 7) * (NB * NH);
#pragma unroll
                for (int j = 0; j < 16; ++j) {
                    f16x8 a0 = *(const f16x8*)(hp0 + (size_t)rA0 * NH + j * 32 + quad * 8);
                    f16x8 a1 = *(const f16x8*)(hp0 + (size_t)(rA0 + 16) * NH + j * 32 + quad * 8);
                    f16x8 w0 = sBf[(nf0 * L1_KC + j) * 64 + lam];
                    f16x8 w1 = sBf[(nf1 * L1_KC + j) * 64 + lam];
                    acc00 = MFMA16(a0, w0, acc00);
                    acc01 = MFMA16(a0, w1, acc01);
                    acc10 = MFMA16(a1, w0, acc10);
                    acc11 = MFMA16(a1, w1, acc11);
                }
            }

            // ---- own phase (gated by go[1]; tight spin, no barrier) ----
            while (__hip_atomic_load(&go[1], __ATOMIC_RELAXED, __HIP_MEMORY_SCOPE_WORKGROUP) <= us)
                ;
            {
                const f16* hpo = (layer ? h1ring : h0ring) + (size_t)((s - 1) & 7) * (NB * NH);
                const int  wb  = layer ? 16 : 2;     // weight-image kc base
#pragma unroll
                for (int j = 0; j < 16; ++j) {
                    f16x8 a0 = *(const f16x8*)(hpo + (size_t)rA0 * NH + j * 32 + quad * 8);
                    f16x8 a1 = *(const f16x8*)(hpo + (size_t)(rA0 + 16) * NH + j * 32 + quad * 8);
                    f16x8 w0 = sBf[(nf0 * KCx + wb + j) * 64 + lam];
                    f16x8 w1 = sBf[(nf1 * KCx + wb + j) * 64 + lam];
                    acc00 = MFMA16(a0, w0, acc00);
                    acc01 = MFMA16(a0, w1, acc01);
                    acc10 = MFMA16(a1, w0, acc10);
                    acc11 = MFMA16(a1, w1, acc11);
                }
            }

            // g/o waves hand their accs to i/f waves
            if (nh == 1) {
                f32x4* e4 = (f32x4*)exch;
                e4[((mh * 2 + 0) * 2 + 0) * 64 + lam] = acc00;   // mf0, gate g
                e4[((mh * 2 + 0) * 2 + 1) * 64 + lam] = acc01;   // mf0, gate o
                e4[((mh * 2 + 1) * 2 + 0) * 64 + lam] = acc10;   // mf1, gate g
                e4[((mh * 2 + 1) * 2 + 1) * 64 + lam] = acc11;   // mf1, gate o
            }
        }

        __syncthreads();   // B3: exch writes visible; all A-loads consumed

        // ---- staleness bound: one acquire-inv per block every RING steps,
        // phase-spread by ht, post-consumption (off the critical detect path).
        if (tid == 128 && ((s & 7) == (ht & 7)))
            (void)__hip_atomic_load((unsigned*)(ws + BAR_OFF), __ATOMIC_ACQUIRE, __HIP_MEMORY_SCOPE_AGENT);

        if (w < 4 && nh == 0) {
            const f32x4* e4 = (const f32x4*)exch;
            f32x4 gg0 = e4[((mh * 2 + 0) * 2 + 0) * 64 + lam];
            f32x4 oo0 = e4[((mh * 2 + 0) * 2 + 1) * 64 + lam];
            f32x4 gg1 = e4[((mh * 2 + 1) * 2 + 0) * 64 + lam];
            f32x4 oo1 = e4[((mh * 2 + 1) * 2 + 1) * 64 + lam];
            f16* hw = (layer ? h1ring : h0ring) + (size_t)(s & 7) * (NB * NH);
#pragma unroll
            for (int mf = 0; mf < 2; ++mf) {
                f32x4 ai = mf ? acc10 : acc00;
                f32x4 af = mf ? acc11 : acc01;
                f32x4 ag = mf ? gg1 : gg0;
                f32x4 ao = mf ? oo1 : oo0;
#pragma unroll
                for (int r = 0; r < 4; ++r) {
                    float iv = ai[r] + bi_i;
                    float fv = af[r] + bi_f;
                    float gv = ag[r] + bi_g;
                    float ov = ao[r] + bi_o;
                    float cc = sigf(fv) * cst[mf][r] + sigf(iv) * tanhx(gv);
                    cst[mf][r] = cc;
                    float hh = sigf(ov) * tanhx(cc);
                    // C/D layout: row = quad*4 + r, col = lane&15
                    f16* dst = &hw[(size_t)(b0 + mh * 32 + mf * 16 + quad * 4 + r) * NH + h0c + col];
                    if (layer) h_store<false>(dst, hh);   // h1: agent (own-L2 dirty)
                    else       h_store<true >(dst, hh);   // h0: system (LLC truth)
                }
            }
        }

        // B4: per-wave vmcnt(0) before s_barrier -> all h stores drained
        // (system at LLC, agent in own L2) before anyone proceeds.
        __syncthreads();

        // publish by the sync wave (never a consumer-side poller)
        if (w == 4 && lam == 0) {
            __hip_atomic_store(flags + (size_t)bid * 32, us + 1u,
                               __ATOMIC_RELAXED, __HIP_MEMORY_SCOPE_AGENT);
            if (needRel)
                __hip_atomic_fetch_add(cntp(gid, s & 7), 1u, __ATOMIC_RELEASE, __HIP_MEMORY_SCOPE_AGENT);
            else
                __hip_atomic_fetch_add(cntp(gid, s & 7), 1u, __ATOMIC_RELAXED, __HIP_MEMORY_SCOPE_AGENT);
        }
    }

    // L1 blocks: one final RELEASE publish (wbl2 flushes dirty agent-scope h1
    // to the LLC) so the FC reader is correct in every mode.
    if (layer == 1 && tid == 0)
        __hip_atomic_fetch_add(finp, 1u, __ATOMIC_RELEASE, __HIP_MEMORY_SCOPE_AGENT);

    // Final FC by block 0: all 128 L1 blocks must have finished step 511.
    if (bid == 0) {
        if (tid == 0) {
            while (__hip_atomic_fetch_add(finp, 0u, __ATOMIC_RELAXED, __HIP_MEMORY_SCOPE_AGENT) < 128u)
                __builtin_amdgcn_s_sleep(8);
            (void)__hip_atomic_load((unsigned*)(ws + BAR_OFF), __ATOMIC_ACQUIRE, __HIP_MEMORY_SCOPE_AGENT);
        }
        __syncthreads();
        if (tid < 256) {
            const f16* hrow = h1ring + (size_t)7 * (NB * NH) + (size_t)tid * NH;  // slot 511&7 = 7
            float acc = fcb[0];
#pragma unroll 4
            for (int j = 0; j < NH; j += 8) {
                f16x8 hv = *(const f16x8*)(hrow + j);
#pragma unroll
                for (int e = 0; e < 8; ++e) acc += fcW[j + e] * (float)hv[e];
            }
            out[tid] = acc;
        }
    }
}

// ---------------------------------------------------------------------------
extern "C" void kernel_launch(void* const* d_in, const int* in_sizes, int n_in,
                              void* d_out, int out_size, void* d_ws, size_t ws_size,
                              hipStream_t stream) {
    const float* x    = (const float*)d_in[0];
    const float* Wih0 = (const float*)d_in[1];
    const float* Whh0 = (const float*)d_in[2];
    const float* bih0 = (const float*)d_in[3];
    const float* bhh0 = (const float*)d_in[4];
    const float* Wih1 = (const float*)d_in[5];
    const float* Whh1 = (const float*)d_in[6];
    const float* bih1 = (const float*)d_in[7];
    const float* bhh1 = (const float*)d_in[8];
    const float* fcW  = (const float*)d_in[9];
    const float* fcb  = (const float*)d_in[10];
    char*  ws  = (char*)d_ws;
    float* out = (float*)d_out;

    if (ws_size < WS_NEED) {  // deterministic failure instead of corruption
        hipMemsetAsync(d_out, 0, (size_t)out_size * sizeof(float), stream);
        return;
    }

    hipFuncSetAttribute(reinterpret_cast<const void*>(lstm_persist),
                        hipFuncAttributeMaxDynamicSharedMemorySize, LDS_SIZE);

    prep_weights<<<1600, 256, 0, stream>>>(Wih0, Whh0, Wih1, Whh1, ws);
    prep_state<<<1100, 256, 0, stream>>>(bih0, bhh0, bih1, bhh1, ws);
    // 256 blocks * 320 threads (4 compute waves + 1 sync wave), 1 block/CU
    lstm_persist<<<256, 320, LDS_SIZE, stream>>>(ws, x, fcW, fcb, out);
}

// Round 4
// 3673.409 us; speedup vs baseline: 1.5266x; 1.5047x over previous
//
#include <hip/hip_runtime.h>

// ---------------------------------------------------------------------------
// 2-layer LSTM (B=256,T=512,H=512,DIN=64) + FC, persistent-kernel wavefront.
// R13: mapping-independent RMW sync + coalesced ring transport.
//  Evidence: R9-R12 (4 different schedules) all ~11us/step -> floor is a
//  shared MECHANISM, not the schedule. Suspects never changed before:
//   (a) h-store transport = 2-byte scatter (64x32B partial-line system
//       write-throughs per block-step) on the critical vmcnt(0) drain,
//   (b) fast-flag path validity rests on the %8=XCD mapping self-check,
//       which can pass vacuously -> relaxed-agent flag visibility rides
//       L2 eviction (~10us, the known metastable floor),
//   (c) fallback detect = 32 closed-loop RMW pollers on ONE LLC line.
//  Fixes:
//   - ring relayout [slot][ht][row][16col]: block output = contiguous 2KB;
//     LDS transpose then 128 lanes x one 16B store (full-line transactions).
//   - detect via per-block flag COUNTERS polled with fetch_add(+0) on 32
//     DISTINCT lines (LLC-fresh regardless of XCD mapping; no same-line
//     serialization; satisfied lanes drop out).
//   - single-mfrag waves: wave owns 16 rows, computes all 4 gates -> no
//     g/o exchange, one less barrier, A-traffic halved, cell wave-local.
//   - RING 8->16; ONE phase-aligned acquire-inv per 16 steps (was 4 full-L2
//     wipes per step per XCD).
//   - sync wave polls step s+1 slack edge during step s compute.
//  XCD handshake + write-through self-test kept as safety only (choose h1
//  store scope / release fallback).
// fp16 MFMA (16x16x32), fp32 accum, c-state in registers.
// ---------------------------------------------------------------------------

typedef _Float16 f16;
typedef _Float16 f16x8 __attribute__((ext_vector_type(8)));
typedef float    f32x4 __attribute__((ext_vector_type(4)));

constexpr int NB   = 256;   // batch
constexpr int NT   = 512;   // time steps
constexpr int NH   = 512;   // hidden
constexpr int NDIN = 64;    // input dim

constexpr int L0_KC = 18;   // K chunks of 32: 64(x) + 512(h0) = 576
constexpr int L1_KC = 32;   // 512(h0) + 512(h1) = 1024
constexpr int L0_IMG_HALVES = 4 * L0_KC * 64 * 8;  // 73728 B per htile
constexpr int L1_IMG_HALVES = 4 * L1_KC * 64 * 8;  // 131072 B per htile

constexpr int RING = 16;          // ring depth (address rotation period)
constexpr int SLOT_F16 = 131072;  // f16 per ring slot (256KB): [ht][row][16]

// ws layout (bytes)
constexpr size_t BAR_OFF   = 0;                        // cnt[slot][group]: 128 lines * 128 B = 16KB
constexpr size_t AUX_OFF   = 16384;                    // handshake/self-test (4 KB)
constexpr size_t BIAS0_OFF = 20480;                    // 2048 f32
constexpr size_t BIAS1_OFF = 28672;                    // 2048 f32
constexpr size_t FLAG_OFF  = 36864;                    // 256 blocks * 128 B = 32KB (word0=steps done, word1=xcd)
constexpr size_t H0R_OFF   = 131072;                   // 16 slots * 256KB = 4MB
constexpr size_t H1R_OFF   = H0R_OFF + (size_t)RING * SLOT_F16 * 2;  // +4MB
constexpr size_t W0I_OFF   = H1R_OFF + (size_t)RING * SLOT_F16 * 2;  // 8519680
constexpr size_t W1I_OFF   = W0I_OFF + 2359296;        // 32 htiles * 73728 B
constexpr size_t WS_NEED   = W1I_OFF + 4194304;        // ~14.4 MB (ws ~15MB known ok)

// LDS layout
constexpr int LDS_STAGE = 131072;   // 2KB h transpose staging
constexpr int LDS_GO    = 139264;   // 2 go words
constexpr int LDS_SIZE  = 139520;

// ---------------------------------------------------------------------------
// Prep: swizzle weights (fp32 -> fp16) into MFMA B-fragment order. (unchanged)
// B-frag layout (16x16x32): lane L holds B[k = (L>>4)*8 + j][n = L&15], j=0..7
// Image element order: [htile][nf(=gate)][kc][lane][8 halves]
// ---------------------------------------------------------------------------
__global__ void prep_weights(const float* __restrict__ Wih0, const float* __restrict__ Whh0,
                             const float* __restrict__ Wih1, const float* __restrict__ Whh1,
                             char* __restrict__ ws) {
    int idx = blockIdx.x * 256 + threadIdx.x;
    const int L0_CH = 32 * 4 * L0_KC * 64;   // 147456
    const int L1_CH = 32 * 4 * L1_KC * 64;   // 262144
    if (idx < L0_CH) {
        int lam = idx & 63;
        int kc  = (idx >> 6) % L0_KC;
        int nf  = ((idx >> 6) / L0_KC) & 3;
        int ht  = idx / (64 * L0_KC * 4);
        int g   = nf * NH + ht * 16 + (lam & 15);
        int kb  = kc * 32 + (lam >> 4) * 8;
        f16x8 v;
#pragma unroll
        for (int j = 0; j < 8; ++j) {
            int k = kb + j;
            float val = (k < NDIN) ? Wih0[(size_t)g * NDIN + k]
                                   : Whh0[(size_t)g * NH + (k - NDIN)];
            v[j] = (f16)val;
        }
        f16* dst = (f16*)(ws + W0I_OFF) + (size_t)ht * L0_IMG_HALVES
                 + ((size_t)(nf * L0_KC + kc) * 64 + lam) * 8;
        *(f16x8*)dst = v;
    } else if (idx < L0_CH + L1_CH) {
        int i2  = idx - L0_CH;
        int lam = i2 & 63;
        int kc  = (i2 >> 6) % L1_KC;
        int nf  = ((i2 >> 6) / L1_KC) & 3;
        int ht  = i2 / (64 * L1_KC * 4);
        int g   = nf * NH + ht * 16 + (lam & 15);
        int kb  = kc * 32 + (lam >> 4) * 8;
        f16x8 v;
#pragma unroll
        for (int j = 0; j < 8; ++j) {
            int k = kb + j;
            float val = (k < NH) ? Wih1[(size_t)g * NH + k]
                                 : Whh1[(size_t)g * NH + (k - NH)];
            v[j] = (f16)val;
        }
        f16* dst = (f16*)(ws + W1I_OFF) + (size_t)ht * L1_IMG_HALVES
                 + ((size_t)(nf * L1_KC + kc) * 64 + lam) * 8;
        *(f16x8*)dst = v;
    }
}

// bias sums + zero sync areas + zero both h rings (8 MB), grid-stride
__global__ void prep_state(const float* __restrict__ bih0, const float* __restrict__ bhh0,
                           const float* __restrict__ bih1, const float* __restrict__ bhh1,
                           char* __restrict__ ws) {
    int idx    = blockIdx.x * 256 + threadIdx.x;
    int stride = gridDim.x * 256;
    if (idx < 2048) {
        ((float*)(ws + BIAS0_OFF))[idx] = bih0[idx] + bhh0[idx];
    } else if (idx < 4096) {
        int i = idx - 2048;
        ((float*)(ws + BIAS1_OFF))[i] = bih1[i] + bhh1[i];
    }
    uint4 z; z.x = z.y = z.z = z.w = 0u;
    for (int i = idx; i < 1280; i += stride)            // BAR (16KB) + AUX (4KB)
        ((uint4*)(ws + BAR_OFF))[i] = z;
    for (int i = idx; i < 2048; i += stride)            // FLAG (32KB)
        ((uint4*)(ws + FLAG_OFF))[i] = z;
    const int RINGU4 = (int)((size_t)2 * RING * SLOT_F16 * 2 / 16);  // 524288
    for (int i = idx; i < RINGU4; i += stride)          // h0 + h1 rings (8MB)
        ((uint4*)(ws + H0R_OFF))[i] = z;
}

// ---------------------------------------------------------------------------
__device__ __forceinline__ float sigf(float x) { return 1.f / (1.f + __expf(-x)); }
__device__ __forceinline__ float tanhx(float x) { float e = __expf(2.f * x); return 1.f - 2.f / (e + 1.f); }

// 8B h store: sys -> LLC write-through (cross-XCD consumers); else agent
// (dirty in own L2; same-XCD consumers read fresh; final FC via release flush).
__device__ __forceinline__ void st8(unsigned long long* p, unsigned long long v, bool sys) {
    if (sys) __hip_atomic_store(p, v, __ATOMIC_RELAXED, __HIP_MEMORY_SCOPE_SYSTEM);
    else     __hip_atomic_store(p, v, __ATOMIC_RELAXED, __HIP_MEMORY_SCOPE_AGENT);
}

// RMW poll: executes at the LLC (agent-scope atomicity) -> never stale.
template <int SLP>
__device__ __forceinline__ void spin_cnt(unsigned* p, unsigned tgt) {
    while (__hip_atomic_fetch_add(p, 0u, __ATOMIC_RELAXED, __HIP_MEMORY_SCOPE_AGENT) < tgt)
        __builtin_amdgcn_s_sleep(SLP);
}

#define MFMA16(a, b, c) __builtin_amdgcn_mfma_f32_16x16x32_f16((a), (b), (c), 0, 0, 0)

__global__ __launch_bounds__(320, 1) void lstm_persist(char* __restrict__ ws,
                                                       const float* __restrict__ xin,
                                                       const float* __restrict__ fcW,
                                                       const float* __restrict__ fcb,
                                                       float* __restrict__ out) {
    extern __shared__ __align__(16) char smem[];
    f16*      sW     = (f16*)smem;                    // W image: up to 128 KB
    f16*      hstage = (f16*)(smem + LDS_STAGE);      // 2KB transpose staging
    unsigned* go     = (unsigned*)(smem + LDS_GO);    // go[0]=slack, go[1]=own

    const int tid  = threadIdx.x;
    const int lam  = tid & 63;
    const int w    = tid >> 6;       // 0..3 compute (= m-frag), 4 sync
    const int col  = lam & 15;
    const int quad = lam >> 4;

    const int bid   = blockIdx.x;
    const int gid   = bid & 7;               // group
    const int layer = gid >> 2;              // 0..1
    const int b0    = (gid & 3) * 64;        // 4 B-tiles of 64
    const int ht    = bid >> 3;              // 32 H-tiles of 16
    const int h0c   = ht * 16;
    const int KCx   = layer ? L1_KC : L0_KC;

    auto cntp = [&](int g, int slot) -> unsigned* {
        return (unsigned*)(ws + BAR_OFF + (size_t)(slot * 8 + g) * 128);
    };
    unsigned* flags = (unsigned*)(ws + FLAG_OFF);         // 128B line per block (word0=step counter)
    unsigned* hsk   = (unsigned*)(ws + AUX_OFF);
    unsigned* trdy  = (unsigned*)(ws + AUX_OFF + 128);
    unsigned* modep = (unsigned*)(ws + AUX_OFF + 256);
    unsigned* finp  = (unsigned*)(ws + AUX_OFF + 384);
    unsigned* tpat  = (unsigned*)(ws + AUX_OFF + 1024);

    // ---- startup: XCD-id handshake + write-through self-test (tid 0) ----
    // fast  = whole group on my XCD (enables agent-scope h1)
    // needRel = system stores do NOT write through -> release publishes
    if (tid == 0) {
        go[0] = 0u; go[1] = 0u;
        unsigned myxid = (unsigned)__builtin_amdgcn_s_getreg((31 << 11) | (0 << 6) | 20) & 0xFu;
        flags[(size_t)bid * 32 + 1] = myxid;
        __hip_atomic_fetch_add(hsk, 1u, __ATOMIC_RELEASE, __HIP_MEMORY_SCOPE_AGENT);
        while (__hip_atomic_fetch_add(hsk, 0u, __ATOMIC_RELAXED, __HIP_MEMORY_SCOPE_AGENT) < 256u)
            __builtin_amdgcn_s_sleep(8);
        (void)__hip_atomic_load(hsk, __ATOMIC_ACQUIRE, __HIP_MEMORY_SCOPE_AGENT);
        unsigned fast = 1u;
        for (int i = 0; i < 32; ++i)
            if (flags[(size_t)(i * 8 + gid) * 32 + 1] != myxid) fast = 0u;
        int chk = 1;
        for (int i = 1; i < 256; ++i)
            if (flags[(size_t)i * 32 + 1] != flags[1]) { chk = i; break; }
        if (bid == 0) {
            for (int i = 0; i < 16; ++i)
                __hip_atomic_store(tpat + i * 16, 0xC0FFEE00u + (unsigned)i,
                                   __ATOMIC_RELAXED, __HIP_MEMORY_SCOPE_SYSTEM);
            asm volatile("s_waitcnt vmcnt(0)" ::: "memory");
            __hip_atomic_fetch_add(trdy, 1u, __ATOMIC_RELAXED, __HIP_MEMORY_SCOPE_AGENT);
        }
        if (bid == chk) {
            while (__hip_atomic_fetch_add(trdy, 0u, __ATOMIC_RELAXED, __HIP_MEMORY_SCOPE_AGENT) < 1u)
                __builtin_amdgcn_s_sleep(8);
            unsigned ok = 1u;
            for (int i = 0; i < 16; ++i)
                if (__hip_atomic_load(tpat + i * 16, __ATOMIC_RELAXED, __HIP_MEMORY_SCOPE_SYSTEM)
                    != 0xC0FFEE00u + (unsigned)i) ok = 0u;
            __hip_atomic_fetch_add(modep, 2u | (ok ? 0u : 1u), __ATOMIC_RELAXED, __HIP_MEMORY_SCOPE_AGENT);
        }
        unsigned mv; int spins = 0;
        while ((mv = __hip_atomic_fetch_add(modep, 0u, __ATOMIC_RELAXED, __HIP_MEMORY_SCOPE_AGENT)) < 2u) {
            __builtin_amdgcn_s_sleep(16);
            if (++spins > (1 << 22)) { mv = 3u; break; }
        }
        ((unsigned*)hstage)[0] = fast;
        ((unsigned*)hstage)[1] = mv & 1u;
    }
    __syncthreads();
    const unsigned fast    = ((unsigned*)hstage)[0];
    const unsigned needRel = ((unsigned*)hstage)[1];
    __syncthreads();

    f16* h0ring = (f16*)(ws + H0R_OFF);
    f16* h1ring = (f16*)(ws + H1R_OFF);
    const float* bias = (const float*)(ws + (layer ? BIAS1_OFF : BIAS0_OFF));
    const f16*   wimg = (const f16*)(ws + (layer ? W1I_OFF : W0I_OFF))
                      + (size_t)ht * (layer ? L1_IMG_HALVES : L0_IMG_HALVES);

    // Stage this block's W slice into LDS once.
    {
        const int n16 = KCx * 4 * 64;
        const uint4* src = (const uint4*)wimg;
        uint4* dst = (uint4*)sW;
        for (int i = tid; i < n16; i += 320) dst[i] = src[i];
    }
    __syncthreads();

    const float bi_i = bias[0 * NH + h0c + col];
    const float bi_f = bias[1 * NH + h0c + col];
    const float bi_g = bias[2 * NH + h0c + col];
    const float bi_o = bias[3 * NH + h0c + col];

    float cst[4];
#pragma unroll
    for (int r = 0; r < 4; ++r) cst[r] = 0.f;

    const f16x8* sBf = (const f16x8*)sW;
    const int rA   = b0 + (w & 3) * 16 + col;           // my m-frag row
    const int rofs = rA * 16 + (quad & 1) * 8;          // f16 offset within slot row area
    const int hq   = (quad >> 1) * 4096;                // htile-parity offset

    // sync-wave prologue: slack(0) + go0=1
    if (w == 4 && lam == 0) {
        if (layer == 1) spin_cnt<4>(cntp(gid - 4, 0), 32u);   // L0 done step 0
        __hip_atomic_store(&go[0], 1u, __ATOMIC_RELAXED, __HIP_MEMORY_SCOPE_WORKGROUP);
    }

    for (int s = 0; s < NT; ++s) {
        const unsigned us = (unsigned)s;

        f32x4 ai = {0.f,0.f,0.f,0.f}, af = {0.f,0.f,0.f,0.f};
        f32x4 ag = {0.f,0.f,0.f,0.f}, ao = {0.f,0.f,0.f,0.f};

        if (w == 4) {
            // ===== SYNC WAVE =====
            // own edge for s: all 32 group flags >= s (distinct-line RMW poll,
            // LLC-fresh under ANY block->XCD mapping; satisfied lanes drop out)
            if (s > 0 && lam < 32) {
                unsigned* fp = flags + (size_t)(lam * 8 + gid) * 32;
                unsigned v = 0u;
                for (;;) {
                    if (v < us)
                        v = __hip_atomic_fetch_add(fp, 0u, __ATOMIC_RELAXED, __HIP_MEMORY_SCOPE_AGENT);
                    if (__all((int)(v >= us))) break;
                    __builtin_amdgcn_s_sleep(2);
                }
            }
            if (lam == 0)
                __hip_atomic_store(&go[1], us + 1u, __ATOMIC_RELAXED, __HIP_MEMORY_SCOPE_WORKGROUP);
            // slack edge for step s+1 (hidden under this step's compute)
            if (lam == 0 && s + 1 < NT) {
                const unsigned t = us + 1u;
                if (layer == 0) {
                    if (t >= (unsigned)RING)   // WAR: L1 partner done t-16
                        spin_cnt<8>(cntp(gid + 4, (int)(t & 15u)), 32u * (t >> 4));
                } else {
                    spin_cnt<4>(cntp(gid - 4, (int)(t & 15u)), 32u * ((t >> 4) + 1u));  // L0 done t
                }
                __hip_atomic_store(&go[0], t + 1u, __ATOMIC_RELAXED, __HIP_MEMORY_SCOPE_WORKGROUP);
            }
        } else {
            // ===== COMPUTE WAVES (wave = one 16-row m-frag, all 4 gates) =====
            if (layer == 0) {
                // x part (no dependency): kc 0..1
                const float* xr = xin + (size_t)rA * (NT * NDIN) + (size_t)s * NDIN + quad * 8;
#pragma unroll
                for (int j = 0; j < 2; ++j) {
                    float4 f0 = *(const float4*)(xr + j * 32);
                    float4 f1 = *(const float4*)(xr + j * 32 + 4);
                    f16x8 a;
                    a[0] = (f16)f0.x; a[1] = (f16)f0.y; a[2] = (f16)f0.z; a[3] = (f16)f0.w;
                    a[4] = (f16)f1.x; a[5] = (f16)f1.y; a[6] = (f16)f1.z; a[7] = (f16)f1.w;
                    ai = MFMA16(a, sBf[(0 * L0_KC + j) * 64 + lam], ai);
                    af = MFMA16(a, sBf[(1 * L0_KC + j) * 64 + lam], af);
                    ag = MFMA16(a, sBf[(2 * L0_KC + j) * 64 + lam], ag);
                    ao = MFMA16(a, sBf[(3 * L0_KC + j) * 64 + lam], ao);
                }
                // WAR gate before anything else touches the ring write slot
                while (__hip_atomic_load(&go[0], __ATOMIC_RELAXED, __HIP_MEMORY_SCOPE_WORKGROUP) <= us)
                    __builtin_amdgcn_s_sleep(1);
            } else {
                // slack phase: h0[s] (gated by go0; L0 leads in steady state)
                while (__hip_atomic_load(&go[0], __ATOMIC_RELAXED, __HIP_MEMORY_SCOPE_WORKGROUP) <= us)
                    __builtin_amdgcn_s_sleep(1);
                const f16* hp0 = h0ring + (size_t)(s & 15) * SLOT_F16;
#pragma unroll
                for (int j = 0; j < 16; ++j) {
                    f16x8 a = *(const f16x8*)(hp0 + (size_t)(2 * j) * 4096 + hq + rofs);
                    ai = MFMA16(a, sBf[(0 * L1_KC + j) * 64 + lam], ai);
                    af = MFMA16(a, sBf[(1 * L1_KC + j) * 64 + lam], af);
                    ag = MFMA16(a, sBf[(2 * L1_KC + j) * 64 + lam], ag);
                    ao = MFMA16(a, sBf[(3 * L1_KC + j) * 64 + lam], ao);
                }
            }

            // own phase (gated by go1; tight spin)
            while (__hip_atomic_load(&go[1], __ATOMIC_RELAXED, __HIP_MEMORY_SCOPE_WORKGROUP) <= us)
                ;
            {
                const f16* hpo = (layer ? h1ring : h0ring) + (size_t)((s + RING - 1) & 15) * SLOT_F16;
                const int  wb  = layer ? 16 : 2;
#pragma unroll
                for (int j = 0; j < 16; ++j) {
                    f16x8 a = *(const f16x8*)(hpo + (size_t)(2 * j) * 4096 + hq + rofs);
                    ai = MFMA16(a, sBf[(0 * KCx + wb + j) * 64 + lam], ai);
                    af = MFMA16(a, sBf[(1 * KCx + wb + j) * 64 + lam], af);
                    ag = MFMA16(a, sBf[(2 * KCx + wb + j) * 64 + lam], ag);
                    ao = MFMA16(a, sBf[(3 * KCx + wb + j) * 64 + lam], ao);
                }
            }

            // cell update, fully wave-local; stage h into LDS (transpose)
#pragma unroll
            for (int r = 0; r < 4; ++r) {
                float iv = ai[r] + bi_i;
                float fv = af[r] + bi_f;
                float gv = ag[r] + bi_g;
                float ov = ao[r] + bi_o;
                float cc = sigf(fv) * cst[r] + sigf(iv) * tanhx(gv);
                cst[r] = cc;
                float hh = sigf(ov) * tanhx(cc);
                hstage[((w & 3) * 16 + quad * 4 + r) * 16 + col] = (f16)hh;
            }
        }

        __syncthreads();   // T: hstage complete (all A-loads of this step consumed)

        // coalesced ring write: 128 lanes x 16B contiguous (2KB block chunk)
        if (tid < 128) {
            const unsigned long long* sp = (const unsigned long long*)hstage;
            unsigned long long v0 = sp[tid * 2], v1 = sp[tid * 2 + 1];
            f16* dstf = (layer ? h1ring : h0ring)
                      + (size_t)(s & 15) * SLOT_F16 + (size_t)ht * 4096
                      + (size_t)b0 * 16 + (size_t)tid * 8;
            bool sys = layer ? (fast == 0u) : true;   // h0 cross-XCD; h1 agent if co-located
            st8((unsigned long long*)dstf, v0, sys);
            st8((unsigned long long*)dstf + 1, v1, sys);
        }

        // staleness bound: ONE aligned acquire-inv per 16 steps (post-consumption,
        // pre-B4 so vmcnt(0) at B4 completes it before anyone's next-step loads).
        if (tid == 128 && ((s & 15) == 15))
            (void)__hip_atomic_load((unsigned*)(ws + BAR_OFF), __ATOMIC_ACQUIRE, __HIP_MEMORY_SCOPE_AGENT);

        __syncthreads();   // B4: per-wave vmcnt(0) -> h data at LLC/L2 before publish

        if (w == 4 && lam == 0) {
            if (needRel) {
                // fallback: wbl2 guarantees data at LLC before each counter lands
                __hip_atomic_fetch_add(cntp(gid, s & 15), 1u, __ATOMIC_RELEASE, __HIP_MEMORY_SCOPE_AGENT);
                if (fast)
                    __hip_atomic_fetch_add(flags + (size_t)bid * 32, 1u, __ATOMIC_RELAXED, __HIP_MEMORY_SCOPE_AGENT);
                else
                    __hip_atomic_fetch_add(flags + (size_t)bid * 32, 1u, __ATOMIC_RELEASE, __HIP_MEMORY_SCOPE_AGENT);
            } else {
                __hip_atomic_fetch_add(flags + (size_t)bid * 32, 1u, __ATOMIC_RELAXED, __HIP_MEMORY_SCOPE_AGENT);
                __hip_atomic_fetch_add(cntp(gid, s & 15), 1u, __ATOMIC_RELAXED, __HIP_MEMORY_SCOPE_AGENT);
            }
        }
    }

    // L1 blocks: final RELEASE (wbl2 flushes agent-dirty h1 to LLC for the FC)
    if (layer == 1 && tid == 0)
        __hip_atomic_fetch_add(finp, 1u, __ATOMIC_RELEASE, __HIP_MEMORY_SCOPE_AGENT);

    // Final FC by block 0: all 128 L1 blocks finished step 511 (slot 15).
    if (bid == 0) {
        if (tid == 0) {
            while (__hip_atomic_fetch_add(finp, 0u, __ATOMIC_RELAXED, __HIP_MEMORY_SCOPE_AGENT) < 128u)
                __builtin_amdgcn_s_sleep(8);
            (void)__hip_atomic_load((unsigned*)(ws + BAR_OFF), __ATOMIC_ACQUIRE, __HIP_MEMORY_SCOPE_AGENT);
        }
        __syncthreads();
        if (tid < 256) {
            const f16* hrow = h1ring + (size_t)15 * SLOT_F16 + (size_t)tid * 16;
            float acc = fcb[0];
#pragma unroll 4
            for (int t2 = 0; t2 < 32; ++t2) {
                f16x8 a = *(const f16x8*)(hrow + t2 * 4096);
                f16x8 b = *(const f16x8*)(hrow + t2 * 4096 + 8);
#pragma unroll
                for (int e = 0; e < 8; ++e)
                    acc += fcW[t2 * 16 + e] * (float)a[e] + fcW[t2 * 16 + 8 + e] * (float)b[e];
            }
            out[tid] = acc;
        }
    }
}

// ---------------------------------------------------------------------------
extern "C" void kernel_launch(void* const* d_in, const int* in_sizes, int n_in,
                              void* d_out, int out_size, void* d_ws, size_t ws_size,
                              hipStream_t stream) {
    const float* x    = (const float*)d_in[0];
    const float* Wih0 = (const float*)d_in[1];
    const float* Whh0 = (const float*)d_in[2];
    const float* bih0 = (const float*)d_in[3];
    const float* bhh0 = (const float*)d_in[4];
    const float* Wih1 = (const float*)d_in[5];
    const float* Whh1 = (const float*)d_in[6];
    const float* bih1 = (const float*)d_in[7];
    const float* bhh1 = (const float*)d_in[8];
    const float* fcW  = (const float*)d_in[9];
    const float* fcb  = (const float*)d_in[10];
    char*  ws  = (char*)d_ws;
    float* out = (float*)d_out;

    if (ws_size < WS_NEED) {  // deterministic failure instead of corruption
        hipMemsetAsync(d_out, 0, (size_t)out_size * sizeof(float), stream);
        return;
    }

    hipFuncSetAttribute(reinterpret_cast<const void*>(lstm_persist),
                        hipFuncAttributeMaxDynamicSharedMemorySize, LDS_SIZE);

    prep_weights<<<1600, 256, 0, stream>>>(Wih0, Whh0, Wih1, Whh1, ws);
    prep_state<<<1100, 256, 0, stream>>>(bih0, bhh0, bih1, bhh1, ws);
    // 256 blocks * 320 threads (4 compute waves + 1 sync wave), 1 block/CU
    lstm_persist<<<256, 320, LDS_SIZE, stream>>>(ws, x, fcW, fcb, out);
}

// Round 5
// 3116.479 us; speedup vs baseline: 1.7994x; 1.1787x over previous
//
#include <hip/hip_runtime.h>

// ---------------------------------------------------------------------------
// 2-layer LSTM (B=256,T=512,H=512,DIN=64) + FC, persistent-kernel wavefront.
// R14: critical edge moved onto the intra-XCD L2, gated by a BEHAVIORAL probe.
//  R13 (coalesced transport + distinct-line RMW) won 1.5x -> confirmed the
//  floor is serialized fabric round-trips (drain/publish/detect/load, each
//  ~0.7-1.2us at MALL). R14 removes the MALL from the critical cycle:
//   - startup probe: each block tokens its flag line pre-handshake; each
//     counts poll ITERATIONS to see all 32 group tokens. Same-XCD = dirty-L2
//     delivery = ~1-2 iters; cross-XCD = ~10us eviction = >=30 iters -> fail.
//     Unanimous vote per group; any doubt -> exact-R13 fallback. The probe
//     measures the very mechanism the data uses (self-validating).
//   - fast mode: ring store = ONE plain 16B write-back store (dirty L2);
//     B4 vmcnt = L2 ack; flag publish = sc0 store; detect = sc0 loads.
//     All critical legs ~0.2-0.3us.
//   - cross-XCD consumers (L1<-h0 slack, WAR, FC) get a DEFERRED system-scope
//     rewrite of the same addresses by wave 3 during the next step's slack
//     window (+ cnt bump after drain) -- MALL latency off the critical path,
//     absorbed by the 16-step ring slack. Identical bytes to both copies.
//   - mixed/fallback modes value-compatible: flag words carry the same
//     absolute step count in both modes; cnt always maintained.
// fp16 MFMA (16x16x32), fp32 accum, c-state in registers.
// ---------------------------------------------------------------------------

typedef _Float16 f16;
typedef _Float16 f16x8 __attribute__((ext_vector_type(8)));
typedef float    f32x4 __attribute__((ext_vector_type(4)));

constexpr int NB   = 256;
constexpr int NT   = 512;
constexpr int NH   = 512;
constexpr int NDIN = 64;

constexpr int L0_KC = 18;   // 64(x) + 512(h0) = 576 = 18*32
constexpr int L1_KC = 32;   // 512(h0) + 512(h1) = 1024
constexpr int L0_IMG_HALVES = 4 * L0_KC * 64 * 8;
constexpr int L1_IMG_HALVES = 4 * L1_KC * 64 * 8;

constexpr int RING = 16;
constexpr int SLOT_F16 = 131072;  // 256KB per slot: [ht][row][16]

constexpr size_t BAR_OFF   = 0;        // cnt[slot][group]: 128 lines * 128B
constexpr size_t AUX_OFF   = 16384;    // handshake/self-test/votes (4KB)
constexpr size_t BIAS0_OFF = 20480;
constexpr size_t BIAS1_OFF = 28672;
constexpr size_t FLAG_OFF  = 36864;    // 256 * 128B (w0=steps done, w2=token)
constexpr size_t H0R_OFF   = 131072;
constexpr size_t H1R_OFF   = H0R_OFF + (size_t)RING * SLOT_F16 * 2;
constexpr size_t W0I_OFF   = H1R_OFF + (size_t)RING * SLOT_F16 * 2;
constexpr size_t W1I_OFF   = W0I_OFF + 2359296;
constexpr size_t WS_NEED   = W1I_OFF + 4194304;   // ~14.4 MB

constexpr int LDS_STAGE = 131072;
constexpr int LDS_GO    = 139264;
constexpr int LDS_SIZE  = 139520;

// ---------------------------------------------------------------------------
__global__ void prep_weights(const float* __restrict__ Wih0, const float* __restrict__ Whh0,
                             const float* __restrict__ Wih1, const float* __restrict__ Whh1,
                             char* __restrict__ ws) {
    int idx = blockIdx.x * 256 + threadIdx.x;
    const int L0_CH = 32 * 4 * L0_KC * 64;
    const int L1_CH = 32 * 4 * L1_KC * 64;
    if (idx < L0_CH) {
        int lam = idx & 63;
        int kc  = (idx >> 6) % L0_KC;
        int nf  = ((idx >> 6) / L0_KC) & 3;
        int ht  = idx / (64 * L0_KC * 4);
        int g   = nf * NH + ht * 16 + (lam & 15);
        int kb  = kc * 32 + (lam >> 4) * 8;
        f16x8 v;
#pragma unroll
        for (int j = 0; j < 8; ++j) {
            int k = kb + j;
            float val = (k < NDIN) ? Wih0[(size_t)g * NDIN + k]
                                   : Whh0[(size_t)g * NH + (k - NDIN)];
            v[j] = (f16)val;
        }
        f16* dst = (f16*)(ws + W0I_OFF) + (size_t)ht * L0_IMG_HALVES
                 + ((size_t)(nf * L0_KC + kc) * 64 + lam) * 8;
        *(f16x8*)dst = v;
    } else if (idx < L0_CH + L1_CH) {
        int i2  = idx - L0_CH;
        int lam = i2 & 63;
        int kc  = (i2 >> 6) % L1_KC;
        int nf  = ((i2 >> 6) / L1_KC) & 3;
        int ht  = i2 / (64 * L1_KC * 4);
        int g   = nf * NH + ht * 16 + (lam & 15);
        int kb  = kc * 32 + (lam >> 4) * 8;
        f16x8 v;
#pragma unroll
        for (int j = 0; j < 8; ++j) {
            int k = kb + j;
            float val = (k < NH) ? Wih1[(size_t)g * NH + k]
                                 : Whh1[(size_t)g * NH + (k - NH)];
            v[j] = (f16)val;
        }
        f16* dst = (f16*)(ws + W1I_OFF) + (size_t)ht * L1_IMG_HALVES
                 + ((size_t)(nf * L1_KC + kc) * 64 + lam) * 8;
        *(f16x8*)dst = v;
    }
}

__global__ void prep_state(const float* __restrict__ bih0, const float* __restrict__ bhh0,
                           const float* __restrict__ bih1, const float* __restrict__ bhh1,
                           char* __restrict__ ws) {
    int idx    = blockIdx.x * 256 + threadIdx.x;
    int stride = gridDim.x * 256;
    if (idx < 2048) {
        ((float*)(ws + BIAS0_OFF))[idx] = bih0[idx] + bhh0[idx];
    } else if (idx < 4096) {
        int i = idx - 2048;
        ((float*)(ws + BIAS1_OFF))[i] = bih1[i] + bhh1[i];
    }
    uint4 z; z.x = z.y = z.z = z.w = 0u;
    for (int i = idx; i < 1280; i += stride)
        ((uint4*)(ws + BAR_OFF))[i] = z;
    for (int i = idx; i < 2048; i += stride)
        ((uint4*)(ws + FLAG_OFF))[i] = z;
    const int RINGU4 = (int)((size_t)2 * RING * SLOT_F16 * 2 / 16);
    for (int i = idx; i < RINGU4; i += stride)
        ((uint4*)(ws + H0R_OFF))[i] = z;
}

// ---------------------------------------------------------------------------
__device__ __forceinline__ float sigf(float x) { return 1.f / (1.f + __expf(-x)); }
__device__ __forceinline__ float tanhx(float x) { float e = __expf(2.f * x); return 1.f - 2.f / (e + 1.f); }

__device__ __forceinline__ void st8_sys(unsigned long long* p, unsigned long long v) {
    __hip_atomic_store(p, v, __ATOMIC_RELAXED, __HIP_MEMORY_SCOPE_SYSTEM);
}

template <int SLP>
__device__ __forceinline__ void spin_cnt(unsigned* p, unsigned tgt) {
    while (__hip_atomic_fetch_add(p, 0u, __ATOMIC_RELAXED, __HIP_MEMORY_SCOPE_AGENT) < tgt)
        __builtin_amdgcn_s_sleep(SLP);
}

#define MFMA16(a, b, c) __builtin_amdgcn_mfma_f32_16x16x32_f16((a), (b), (c), 0, 0, 0)

__global__ __launch_bounds__(320, 1) void lstm_persist(char* __restrict__ ws,
                                                       const float* __restrict__ xin,
                                                       const float* __restrict__ fcW,
                                                       const float* __restrict__ fcb,
                                                       float* __restrict__ out) {
    extern __shared__ __align__(16) char smem[];
    f16*      sW     = (f16*)smem;
    f16*      hstage = (f16*)(smem + LDS_STAGE);
    unsigned* go     = (unsigned*)(smem + LDS_GO);

    const int tid  = threadIdx.x;
    const int lam  = tid & 63;
    const int w    = tid >> 6;       // 0..3 compute (= m-frag), 4 sync
    const int col  = lam & 15;
    const int quad = lam >> 4;

    const int bid   = blockIdx.x;
    const int gid   = bid & 7;
    const int layer = gid >> 2;
    const int b0    = (gid & 3) * 64;
    const int ht    = bid >> 3;
    const int h0c   = ht * 16;
    const int KCx   = layer ? L1_KC : L0_KC;

    auto cntp = [&](int g, int slot) -> unsigned* {
        return (unsigned*)(ws + BAR_OFF + (size_t)(slot * 8 + g) * 128);
    };
    unsigned* flags = (unsigned*)(ws + FLAG_OFF);
    unsigned* hsk   = (unsigned*)(ws + AUX_OFF);
    unsigned* trdy  = (unsigned*)(ws + AUX_OFF + 128);
    unsigned* modep = (unsigned*)(ws + AUX_OFF + 256);
    unsigned* finp  = (unsigned*)(ws + AUX_OFF + 384);
    unsigned* tpat  = (unsigned*)(ws + AUX_OFF + 1024);
    unsigned* gvote = (unsigned*)(ws + AUX_OFF + 2048);   // 8 groups * 128B

    // ---- startup phase 1: token + handshake + write-through self-test ----
    if (tid == 0) {
        go[0] = 0u; go[1] = 0u;
        // probe token FIRST (pre-handshake): same-XCD peers will see it L2-fast
        __hip_atomic_store(flags + (size_t)bid * 32 + 2, 0x5EED0000u + (unsigned)bid,
                           __ATOMIC_RELAXED, __HIP_MEMORY_SCOPE_AGENT);
        __hip_atomic_fetch_add(hsk, 1u, __ATOMIC_RELEASE, __HIP_MEMORY_SCOPE_AGENT);
        while (__hip_atomic_fetch_add(hsk, 0u, __ATOMIC_RELAXED, __HIP_MEMORY_SCOPE_AGENT) < 256u)
            __builtin_amdgcn_s_sleep(8);
        // write-through self-test (needRel fallback), checker = block 1
        if (bid == 0) {
            for (int i = 0; i < 16; ++i)
                __hip_atomic_store(tpat + i * 16, 0xC0FFEE00u + (unsigned)i,
                                   __ATOMIC_RELAXED, __HIP_MEMORY_SCOPE_SYSTEM);
            asm volatile("s_waitcnt vmcnt(0)" ::: "memory");
            __hip_atomic_fetch_add(trdy, 1u, __ATOMIC_RELAXED, __HIP_MEMORY_SCOPE_AGENT);
        }
        if (bid == 1) {
            while (__hip_atomic_fetch_add(trdy, 0u, __ATOMIC_RELAXED, __HIP_MEMORY_SCOPE_AGENT) < 1u)
                __builtin_amdgcn_s_sleep(8);
            unsigned ok = 1u;
            for (int i = 0; i < 16; ++i)
                if (__hip_atomic_load(tpat + i * 16, __ATOMIC_RELAXED, __HIP_MEMORY_SCOPE_SYSTEM)
                    != 0xC0FFEE00u + (unsigned)i) ok = 0u;
            __hip_atomic_fetch_add(modep, 2u | (ok ? 0u : 1u), __ATOMIC_RELAXED, __HIP_MEMORY_SCOPE_AGENT);
        }
        unsigned mv; int spins = 0;
        while ((mv = __hip_atomic_fetch_add(modep, 0u, __ATOMIC_RELAXED, __HIP_MEMORY_SCOPE_AGENT)) < 2u) {
            __builtin_amdgcn_s_sleep(16);
            if (++spins > (1 << 22)) { mv = 3u; break; }
        }
        ((unsigned*)hstage)[1] = mv & 1u;
    }
    __syncthreads();
    const unsigned needRel = ((unsigned*)hstage)[1];
    __syncthreads();

    // ---- startup phase 2: behavioral co-location probe (wave 0) ----
    // Count poll iterations until all 32 group tokens visible via sc0 loads.
    // Same-XCD (dirty-L2 delivery): ~1-2 iters. Cross-XCD (eviction): >=30.
    if (tid < 64) {
        unsigned seen = (lam < 32) ? 0u : 1u;
        unsigned expv = 0x5EED0000u + (unsigned)(lam * 8 + gid);
        int it = 0, done_at = 1 << 30;
        for (;;) {
            if (!seen && lam < 32) {
                unsigned v = __hip_atomic_load(flags + (size_t)(lam * 8 + gid) * 32 + 2,
                                               __ATOMIC_RELAXED, __HIP_MEMORY_SCOPE_AGENT);
                if (v == expv) seen = 1u;
            }
            ++it;
            if (__all((int)seen)) { done_at = it; break; }
            if (it >= 64) break;
        }
        unsigned ok = (done_at <= 12) ? 1u : 0u;
        if (lam == 0)
            __hip_atomic_fetch_add(gvote + (size_t)gid * 32, 0x10000u | ok,
                                   __ATOMIC_RELAXED, __HIP_MEMORY_SCOPE_AGENT);
    }
    __syncthreads();
    if (tid == 0) {
        unsigned gv = 0u; int sp2 = 0;
        for (;;) {
            gv = __hip_atomic_fetch_add(gvote + (size_t)gid * 32, 0u,
                                        __ATOMIC_RELAXED, __HIP_MEMORY_SCOPE_AGENT);
            if ((gv >> 16) >= 32u) break;
            __builtin_amdgcn_s_sleep(8);
            if (++sp2 > (1 << 20)) { gv = 0u; break; }
        }
        ((unsigned*)hstage)[0] = (((gv >> 16) >= 32u) && ((gv & 0xFFFFu) == 32u)) ? 1u : 0u;
    }
    __syncthreads();
    const unsigned fastgrp = ((unsigned*)hstage)[0];   // unanimous within group
    unsigned       fastE1  = fastgrp;                  // sync wave may demote
    __syncthreads();

    f16* h0ring = (f16*)(ws + H0R_OFF);
    f16* h1ring = (f16*)(ws + H1R_OFF);
    const float* bias = (const float*)(ws + (layer ? BIAS1_OFF : BIAS0_OFF));
    const f16*   wimg = (const f16*)(ws + (layer ? W1I_OFF : W0I_OFF))
                      + (size_t)ht * (layer ? L1_IMG_HALVES : L0_IMG_HALVES);

    {
        const int n16 = KCx * 4 * 64;
        const uint4* src = (const uint4*)wimg;
        uint4* dst = (uint4*)sW;
        for (int i = tid; i < n16; i += 320) dst[i] = src[i];
    }
    __syncthreads();

    const float bi_i = bias[0 * NH + h0c + col];
    const float bi_f = bias[1 * NH + h0c + col];
    const float bi_g = bias[2 * NH + h0c + col];
    const float bi_o = bias[3 * NH + h0c + col];

    float cst[4];
#pragma unroll
    for (int r = 0; r < 4; ++r) cst[r] = 0.f;

    const f16x8* sBf = (const f16x8*)sW;
    const int rA   = b0 + (w & 3) * 16 + col;
    const int rofs = rA * 16 + (quad & 1) * 8;
    const int hq   = (quad >> 1) * 4096;

    // deferred sys-copy registers (wave 3, fast L0 only)
    unsigned long long pr0 = 0, pr1 = 0, pr2 = 0, pr3 = 0;
    unsigned long long* const sysbase =
        (unsigned long long*)((layer ? h1ring : h0ring)) ;  // recomputed per step

    if (w == 4 && lam == 0) {
        if (layer == 1) spin_cnt<4>(cntp(gid - 4, 0), 32u);   // L0 done step 0
        __hip_atomic_store(&go[0], 1u, __ATOMIC_RELAXED, __HIP_MEMORY_SCOPE_WORKGROUP);
    }

    for (int s = 0; s < NT; ++s) {
        const unsigned us = (unsigned)s;

        f32x4 ai = {0.f,0.f,0.f,0.f}, af = {0.f,0.f,0.f,0.f};
        f32x4 ag = {0.f,0.f,0.f,0.f}, ao = {0.f,0.f,0.f,0.f};

        if (w == 4) {
            // ===== SYNC WAVE: pure poller/relay =====
            if (s > 0) {
                if (fastE1) {
                    int it = 0;
                    for (;;) {
                        unsigned v = 0xFFFFFFFFu;
                        if (lam < 32)
                            v = __hip_atomic_load(flags + (size_t)(lam * 8 + gid) * 32,
                                                  __ATOMIC_RELAXED, __HIP_MEMORY_SCOPE_AGENT);
                        if (__all((int)(v >= us))) break;
                        if (++it > 20000) { fastE1 = 0u; break; }
                    }
                }
                if (!fastE1) {   // RMW-fresh fallback poll (distinct lines)
                    for (;;) {
                        unsigned v = 0xFFFFFFFFu;
                        if (lam < 32)
                            v = __hip_atomic_fetch_add(flags + (size_t)(lam * 8 + gid) * 32, 0u,
                                                       __ATOMIC_RELAXED, __HIP_MEMORY_SCOPE_AGENT);
                        if (__all((int)(v >= us))) break;
                        __builtin_amdgcn_s_sleep(2);
                    }
                }
            }
            if (lam == 0)
                __hip_atomic_store(&go[1], us + 1u, __ATOMIC_RELAXED, __HIP_MEMORY_SCOPE_WORKGROUP);
            if (lam == 0 && s + 1 < NT) {   // slack edge for s+1
                const unsigned t = us + 1u;
                if (layer == 0) {
                    if (t >= (unsigned)RING)
                        spin_cnt<8>(cntp(gid + 4, (int)(t & 15u)), 32u * (t >> 4));
                } else {
                    spin_cnt<4>(cntp(gid - 4, (int)(t & 15u)), 32u * ((t >> 4) + 1u));
                }
                __hip_atomic_store(&go[0], t + 1u, __ATOMIC_RELAXED, __HIP_MEMORY_SCOPE_WORKGROUP);
            }
        } else {
            // ===== COMPUTE WAVES =====
            if (layer == 0) {
                // deferred sys copy of step s-1 (fast mode, wave 3): issue now,
                // drain+cnt after the x-GEMM (latency hidden under slack work)
                if (fastgrp && w == 3 && s > 0) {
                    unsigned long long* d = (unsigned long long*)
                        ((char*)h0ring + ((size_t)((s - 1) & 15) * SLOT_F16 + (size_t)ht * 4096
                                          + (size_t)b0 * 16) * 2) + (size_t)lam * 4;
                    st8_sys(d + 0, pr0); st8_sys(d + 1, pr1);
                    st8_sys(d + 2, pr2); st8_sys(d + 3, pr3);
                }
                const float* xr = xin + (size_t)rA * (NT * NDIN) + (size_t)s * NDIN + quad * 8;
#pragma unroll
                for (int j = 0; j < 2; ++j) {
                    float4 f0 = *(const float4*)(xr + j * 32);
                    float4 f1 = *(const float4*)(xr + j * 32 + 4);
                    f16x8 a;
                    a[0] = (f16)f0.x; a[1] = (f16)f0.y; a[2] = (f16)f0.z; a[3] = (f16)f0.w;
                    a[4] = (f16)f1.x; a[5] = (f16)f1.y; a[6] = (f16)f1.z; a[7] = (f16)f1.w;
                    ai = MFMA16(a, sBf[(0 * L0_KC + j) * 64 + lam], ai);
                    af = MFMA16(a, sBf[(1 * L0_KC + j) * 64 + lam], af);
                    ag = MFMA16(a, sBf[(2 * L0_KC + j) * 64 + lam], ag);
                    ao = MFMA16(a, sBf[(3 * L0_KC + j) * 64 + lam], ao);
                }
                if (fastgrp && w == 3 && s > 0) {
                    asm volatile("s_waitcnt vmcnt(0)" ::: "memory");
                    if (lam == 0) {
                        if (needRel)
                            __hip_atomic_fetch_add(cntp(gid, (s - 1) & 15), 1u, __ATOMIC_RELEASE, __HIP_MEMORY_SCOPE_AGENT);
                        else
                            __hip_atomic_fetch_add(cntp(gid, (s - 1) & 15), 1u, __ATOMIC_RELAXED, __HIP_MEMORY_SCOPE_AGENT);
                    }
                }
                // WAR gate before the ring write of slot s&15
                while (__hip_atomic_load(&go[0], __ATOMIC_RELAXED, __HIP_MEMORY_SCOPE_WORKGROUP) <= us)
                    __builtin_amdgcn_s_sleep(1);
            } else {
                while (__hip_atomic_load(&go[0], __ATOMIC_RELAXED, __HIP_MEMORY_SCOPE_WORKGROUP) <= us)
                    __builtin_amdgcn_s_sleep(1);
                const f16* hp0 = h0ring + (size_t)(s & 15) * SLOT_F16;
#pragma unroll
                for (int j = 0; j < 16; ++j) {
                    f16x8 a = *(const f16x8*)(hp0 + (size_t)(2 * j) * 4096 + hq + rofs);
                    ai = MFMA16(a, sBf[(0 * L1_KC + j) * 64 + lam], ai);
                    af = MFMA16(a, sBf[(1 * L1_KC + j) * 64 + lam], af);
                    ag = MFMA16(a, sBf[(2 * L1_KC + j) * 64 + lam], ag);
                    ao = MFMA16(a, sBf[(3 * L1_KC + j) * 64 + lam], ao);
                }
            }

            while (__hip_atomic_load(&go[1], __ATOMIC_RELAXED, __HIP_MEMORY_SCOPE_WORKGROUP) <= us)
                ;
            {
                const f16* hpo = (layer ? h1ring : h0ring) + (size_t)((s + RING - 1) & 15) * SLOT_F16;
                const int  wb  = layer ? 16 : 2;
#pragma unroll
                for (int j = 0; j < 16; ++j) {
                    f16x8 a = *(const f16x8*)(hpo + (size_t)(2 * j) * 4096 + hq + rofs);
                    ai = MFMA16(a, sBf[(0 * KCx + wb + j) * 64 + lam], ai);
                    af = MFMA16(a, sBf[(1 * KCx + wb + j) * 64 + lam], af);
                    ag = MFMA16(a, sBf[(2 * KCx + wb + j) * 64 + lam], ag);
                    ao = MFMA16(a, sBf[(3 * KCx + wb + j) * 64 + lam], ao);
                }
            }

#pragma unroll
            for (int r = 0; r < 4; ++r) {
                float iv = ai[r] + bi_i;
                float fv = af[r] + bi_f;
                float gv = ag[r] + bi_g;
                float ov = ao[r] + bi_o;
                float cc = sigf(fv) * cst[r] + sigf(iv) * tanhx(gv);
                cst[r] = cc;
                float hh = sigf(ov) * tanhx(cc);
                hstage[((w & 3) * 16 + quad * 4 + r) * 16 + col] = (f16)hh;
            }
        }

        __syncthreads();   // T: hstage complete; all A-loads of this step consumed

        // ring write: fast = one plain 16B write-back store (dirty L2);
        // fallback = 2x8B system write-through (R13)
        if (tid < 128) {
            f16* dstf = (layer ? h1ring : h0ring)
                      + (size_t)(s & 15) * SLOT_F16 + (size_t)ht * 4096
                      + (size_t)b0 * 16 + (size_t)tid * 8;
            if (fastgrp) {
                *(uint4*)dstf = ((const uint4*)hstage)[tid];
            } else {
                const unsigned long long* sp = (const unsigned long long*)hstage;
                st8_sys((unsigned long long*)dstf, sp[tid * 2]);
                st8_sys((unsigned long long*)dstf + 1, sp[tid * 2 + 1]);
            }
        }
        // wave 3 captures hstage for next step's deferred sys copy (fast L0)
        if (fastgrp && layer == 0 && w == 3) {
            const unsigned long long* sp = (const unsigned long long*)hstage;
            pr0 = sp[lam * 4 + 0]; pr1 = sp[lam * 4 + 1];
            pr2 = sp[lam * 4 + 2]; pr3 = sp[lam * 4 + 3];
        }

        // staleness bound: one aligned acquire-inv per 16 steps
        if (tid == 128 && ((s & 15) == 15))
            (void)__hip_atomic_load((unsigned*)(ws + BAR_OFF), __ATOMIC_ACQUIRE, __HIP_MEMORY_SCOPE_AGENT);

        __syncthreads();   // B4: stores drained (L2 ack fast path / MALL fallback)

        if (tid == 192) {  // wave-3 lane 0: publisher
            if (fastgrp) {
                __hip_atomic_store(flags + (size_t)bid * 32, us + 1u,
                                   __ATOMIC_RELAXED, __HIP_MEMORY_SCOPE_AGENT);
                if (layer == 1) {   // no sys copy needed; progress cnt now
                    __hip_atomic_fetch_add(cntp(gid, s & 15), 1u, __ATOMIC_RELAXED, __HIP_MEMORY_SCOPE_AGENT);
                }
                // fast L0: cnt deferred to next step (after sys-copy drain)
            } else {
                if (needRel)
                    __hip_atomic_fetch_add(cntp(gid, s & 15), 1u, __ATOMIC_RELEASE, __HIP_MEMORY_SCOPE_AGENT);
                else
                    __hip_atomic_fetch_add(cntp(gid, s & 15), 1u, __ATOMIC_RELAXED, __HIP_MEMORY_SCOPE_AGENT);
                __hip_atomic_fetch_add(flags + (size_t)bid * 32, 1u,
                                       __ATOMIC_RELAXED, __HIP_MEMORY_SCOPE_AGENT);
            }
        }
    }

    // epilogue: fast-L0 deferred sys copy + cnt for step 511
    if (fastgrp && layer == 0 && w == 3) {
        unsigned long long* d = (unsigned long long*)
            ((char*)h0ring + ((size_t)15 * SLOT_F16 + (size_t)ht * 4096
                              + (size_t)b0 * 16) * 2) + (size_t)lam * 4;
        st8_sys(d + 0, pr0); st8_sys(d + 1, pr1);
        st8_sys(d + 2, pr2); st8_sys(d + 3, pr3);
        asm volatile("s_waitcnt vmcnt(0)" ::: "memory");
        if (lam == 0) {
            if (needRel)
                __hip_atomic_fetch_add(cntp(gid, 15), 1u, __ATOMIC_RELEASE, __HIP_MEMORY_SCOPE_AGENT);
            else
                __hip_atomic_fetch_add(cntp(gid, 15), 1u, __ATOMIC_RELAXED, __HIP_MEMORY_SCOPE_AGENT);
        }
    }

    // L1 blocks: final RELEASE (wbl2 flushes agent-dirty h1 to LLC for the FC)
    if (layer == 1 && tid == 0)
        __hip_atomic_fetch_add(finp, 1u, __ATOMIC_RELEASE, __HIP_MEMORY_SCOPE_AGENT);

    if (bid == 0) {
        if (tid == 0) {
            while (__hip_atomic_fetch_add(finp, 0u, __ATOMIC_RELAXED, __HIP_MEMORY_SCOPE_AGENT) < 128u)
                __builtin_amdgcn_s_sleep(8);
            (void)__hip_atomic_load((unsigned*)(ws + BAR_OFF), __ATOMIC_ACQUIRE, __HIP_MEMORY_SCOPE_AGENT);
        }
        __syncthreads();
        if (tid < 256) {
            const f16* hrow = h1ring + (size_t)15 * SLOT_F16 + (size_t)tid * 16;
            float acc = fcb[0];
#pragma unroll 4
            for (int t2 = 0; t2 < 32; ++t2) {
                f16x8 a = *(const f16x8*)(hrow + t2 * 4096);
                f16x8 b = *(const f16x8*)(hrow + t2 * 4096 + 8);
#pragma unroll
                for (int e = 0; e < 8; ++e)
                    acc += fcW[t2 * 16 + e] * (float)a[e] + fcW[t2 * 16 + 8 + e] * (float)b[e];
            }
            out[tid] = acc;
        }
    }
}

// ---------------------------------------------------------------------------
extern "C" void kernel_launch(void* const* d_in, const int* in_sizes, int n_in,
                              void* d_out, int out_size, void* d_ws, size_t ws_size,
                              hipStream_t stream) {
    const float* x    = (const float*)d_in[0];
    const float* Wih0 = (const float*)d_in[1];
    const float* Whh0 = (const float*)d_in[2];
    const float* bih0 = (const float*)d_in[3];
    const float* bhh0 = (const float*)d_in[4];
    const float* Wih1 = (const float*)d_in[5];
    const float* Whh1 = (const float*)d_in[6];
    const float* bih1 = (const float*)d_in[7];
    const float* bhh1 = (const float*)d_in[8];
    const float* fcW  = (const float*)d_in[9];
    const float* fcb  = (const float*)d_in[10];
    char*  ws  = (char*)d_ws;
    float* out = (float*)d_out;

    if (ws_size < WS_NEED) {
        hipMemsetAsync(d_out, 0, (size_t)out_size * sizeof(float), stream);
        return;
    }

    hipFuncSetAttribute(reinterpret_cast<const void*>(lstm_persist),
                        hipFuncAttributeMaxDynamicSharedMemorySize, LDS_SIZE);

    prep_weights<<<1600, 256, 0, stream>>>(Wih0, Whh0, Wih1, Whh1, ws);
    prep_state<<<1100, 256, 0, stream>>>(bih0, bhh0, bih1, bhh1, ws);
    lstm_persist<<<256, 320, LDS_SIZE, stream>>>(ws, x, fcW, fcb, out);
}

// Round 7
// 3026.877 us; speedup vs baseline: 1.8526x; 1.0296x over previous
//
#include <hip/hip_runtime.h>

// ---------------------------------------------------------------------------
// 2-layer LSTM (B=256,T=512,H=512,DIN=64) + FC, persistent-kernel wavefront.
// R16: R15 resubmission, hardened. R15 died at container level twice (no
// counters). Audit found no protocol deadlock; to separate infra-flake from
// kernel-hang and de-risk:
//  - RING reverted to 16 (the exact ring geometry/inv cadence of the PASSING
//    R13/R14 runs; R15's RING=8 was an unforced change).
//  - EVERY spin watchdog-bounded (~1000x expected wait): a protocol stall now
//    terminates (visible wrong answer) instead of hanging the container.
// R15's performance changes retained verbatim:
//  1. compute waves SELF-DETECT the own edge: lanes 0-31 poll the 32 group
//     flag lines via sc0 loads (probe-validated mechanism), sleepy spin,
//     per-wave RMW demotion. No wave-4 relay -> no shared-SIMD starvation
//     (R14's wave4 shared SIMD0 with a tight-spinning wave0).
//  2. all spins s_sleep (no issue-slot monopoly).
//  3. L0 wave-3 sys-copy vmcnt(0) drain + cnt bump post-cell (hidden under
//     GEMM; was a pre-barrier MALL stall).
// Probe, self-test, value-compatible flag/cnt protocol: unchanged from R14.
// fp16 MFMA (16x16x32), fp32 accum, c-state in registers.
// ---------------------------------------------------------------------------

typedef _Float16 f16;
typedef _Float16 f16x8 __attribute__((ext_vector_type(8)));
typedef float    f32x4 __attribute__((ext_vector_type(4)));

constexpr int NB   = 256;
constexpr int NT   = 512;
constexpr int NH   = 512;
constexpr int NDIN = 64;

constexpr int L0_KC = 18;   // 64(x) + 512(h0) = 576 = 18*32
constexpr int L1_KC = 32;   // 512(h0) + 512(h1) = 1024
constexpr int L0_IMG_HALVES = 4 * L0_KC * 64 * 8;
constexpr int L1_IMG_HALVES = 4 * L1_KC * 64 * 8;

constexpr int RING = 16;
constexpr int SLOT_F16 = 131072;  // 256KB per slot: [ht][row][16]

constexpr size_t BAR_OFF   = 0;        // cnt[slot][group]: 128 lines * 128B
constexpr size_t AUX_OFF   = 16384;
constexpr size_t BIAS0_OFF = 20480;
constexpr size_t BIAS1_OFF = 28672;
constexpr size_t FLAG_OFF  = 36864;    // 256 * 128B (w0=steps done, w2=token)
constexpr size_t H0R_OFF   = 131072;
constexpr size_t H1R_OFF   = H0R_OFF + (size_t)RING * SLOT_F16 * 2;   // +4MB
constexpr size_t W0I_OFF   = H1R_OFF + (size_t)RING * SLOT_F16 * 2;   // +4MB
constexpr size_t W1I_OFF   = W0I_OFF + 2359296;
constexpr size_t WS_NEED   = W1I_OFF + 4194304;   // ~14.4 MB (passed in R13/R14)

constexpr int LDS_STAGE = 131072;
constexpr int LDS_GO    = 139264;
constexpr int LDS_SIZE  = 139520;

constexpr int WDOG = 1 << 20;   // spin watchdog (~1000x expected wait)

// ---------------------------------------------------------------------------
__global__ void prep_weights(const float* __restrict__ Wih0, const float* __restrict__ Whh0,
                             const float* __restrict__ Wih1, const float* __restrict__ Whh1,
                             char* __restrict__ ws) {
    int idx = blockIdx.x * 256 + threadIdx.x;
    const int L0_CH = 32 * 4 * L0_KC * 64;
    const int L1_CH = 32 * 4 * L1_KC * 64;
    if (idx < L0_CH) {
        int lam = idx & 63;
        int kc  = (idx >> 6) % L0_KC;
        int nf  = ((idx >> 6) / L0_KC) & 3;
        int ht  = idx / (64 * L0_KC * 4);
        int g   = nf * NH + ht * 16 + (lam & 15);
        int kb  = kc * 32 + (lam >> 4) * 8;
        f16x8 v;
#pragma unroll
        for (int j = 0; j < 8; ++j) {
            int k = kb + j;
            float val = (k < NDIN) ? Wih0[(size_t)g * NDIN + k]
                                   : Whh0[(size_t)g * NH + (k - NDIN)];
            v[j] = (f16)val;
        }
        f16* dst = (f16*)(ws + W0I_OFF) + (size_t)ht * L0_IMG_HALVES
                 + ((size_t)(nf * L0_KC + kc) * 64 + lam) * 8;
        *(f16x8*)dst = v;
    } else if (idx < L0_CH + L1_CH) {
        int i2  = idx - L0_CH;
        int lam = i2 & 63;
        int kc  = (i2 >> 6) % L1_KC;
        int nf  = ((i2 >> 6) / L1_KC) & 3;
        int ht  = i2 / (64 * L1_KC * 4);
        int g   = nf * NH + ht * 16 + (lam & 15);
        int kb  = kc * 32 + (lam >> 4) * 8;
        f16x8 v;
#pragma unroll
        for (int j = 0; j < 8; ++j) {
            int k = kb + j;
            float val = (k < NH) ? Wih1[(size_t)g * NH + k]
                                 : Whh1[(size_t)g * NH + (k - NH)];
            v[j] = (f16)val;
        }
        f16* dst = (f16*)(ws + W1I_OFF) + (size_t)ht * L1_IMG_HALVES
                 + ((size_t)(nf * L1_KC + kc) * 64 + lam) * 8;
        *(f16x8*)dst = v;
    }
}

__global__ void prep_state(const float* __restrict__ bih0, const float* __restrict__ bhh0,
                           const float* __restrict__ bih1, const float* __restrict__ bhh1,
                           char* __restrict__ ws) {
    int idx    = blockIdx.x * 256 + threadIdx.x;
    int stride = gridDim.x * 256;
    if (idx < 2048) {
        ((float*)(ws + BIAS0_OFF))[idx] = bih0[idx] + bhh0[idx];
    } else if (idx < 4096) {
        int i = idx - 2048;
        ((float*)(ws + BIAS1_OFF))[i] = bih1[i] + bhh1[i];
    }
    uint4 z; z.x = z.y = z.z = z.w = 0u;
    for (int i = idx; i < 1280; i += stride)            // BAR (16KB) + AUX (4KB)
        ((uint4*)(ws + BAR_OFF))[i] = z;
    for (int i = idx; i < 2048; i += stride)            // FLAG (32KB)
        ((uint4*)(ws + FLAG_OFF))[i] = z;
    const int RINGU4 = (int)((size_t)2 * RING * SLOT_F16 * 2 / 16);  // 8MB total
    for (int i = idx; i < RINGU4; i += stride)
        ((uint4*)(ws + H0R_OFF))[i] = z;
}

// ---------------------------------------------------------------------------
__device__ __forceinline__ float sigf(float x) { return 1.f / (1.f + __expf(-x)); }
__device__ __forceinline__ float tanhx(float x) { float e = __expf(2.f * x); return 1.f - 2.f / (e + 1.f); }

__device__ __forceinline__ void st8_sys(unsigned long long* p, unsigned long long v) {
    __hip_atomic_store(p, v, __ATOMIC_RELAXED, __HIP_MEMORY_SCOPE_SYSTEM);
}

// RMW poll at the LLC (never stale), watchdog-bounded.
template <int SLP>
__device__ __forceinline__ void spin_cnt(unsigned* p, unsigned tgt) {
    int it = 0;
    while (__hip_atomic_fetch_add(p, 0u, __ATOMIC_RELAXED, __HIP_MEMORY_SCOPE_AGENT) < tgt) {
        __builtin_amdgcn_s_sleep(SLP);
        if (++it > WDOG) break;   // terminate rather than hang
    }
}

#define MFMA16(a, b, c) __builtin_amdgcn_mfma_f32_16x16x32_f16((a), (b), (c), 0, 0, 0)

__global__ __launch_bounds__(320, 1) void lstm_persist(char* __restrict__ ws,
                                                       const float* __restrict__ xin,
                                                       const float* __restrict__ fcW,
                                                       const float* __restrict__ fcb,
                                                       float* __restrict__ out) {
    extern __shared__ __align__(16) char smem[];
    f16*      sW     = (f16*)smem;
    f16*      hstage = (f16*)(smem + LDS_STAGE);
    unsigned* go     = (unsigned*)(smem + LDS_GO);    // go[0]=slack, go[1]=own (fallback only)

    const int tid  = threadIdx.x;
    const int lam  = tid & 63;
    const int w    = tid >> 6;       // 0..3 compute (= m-frag), 4 sync
    const int col  = lam & 15;
    const int quad = lam >> 4;

    const int bid   = blockIdx.x;
    const int gid   = bid & 7;
    const int layer = gid >> 2;
    const int b0    = (gid & 3) * 64;
    const int ht    = bid >> 3;
    const int h0c   = ht * 16;
    const int KCx   = layer ? L1_KC : L0_KC;

    auto cntp = [&](int g, int slot) -> unsigned* {
        return (unsigned*)(ws + BAR_OFF + (size_t)(slot * 8 + g) * 128);
    };
    unsigned* flags = (unsigned*)(ws + FLAG_OFF);
    unsigned* hsk   = (unsigned*)(ws + AUX_OFF);
    unsigned* trdy  = (unsigned*)(ws + AUX_OFF + 128);
    unsigned* modep = (unsigned*)(ws + AUX_OFF + 256);
    unsigned* finp  = (unsigned*)(ws + AUX_OFF + 384);
    unsigned* tpat  = (unsigned*)(ws + AUX_OFF + 1024);
    unsigned* gvote = (unsigned*)(ws + AUX_OFF + 2048);

    // ---- startup phase 1: token + handshake + write-through self-test ----
    if (tid == 0) {
        go[0] = 0u; go[1] = 0u;
        __hip_atomic_store(flags + (size_t)bid * 32 + 2, 0x5EED0000u + (unsigned)bid,
                           __ATOMIC_RELAXED, __HIP_MEMORY_SCOPE_AGENT);
        __hip_atomic_fetch_add(hsk, 1u, __ATOMIC_RELEASE, __HIP_MEMORY_SCOPE_AGENT);
        {
            int it = 0;
            while (__hip_atomic_fetch_add(hsk, 0u, __ATOMIC_RELAXED, __HIP_MEMORY_SCOPE_AGENT) < 256u) {
                __builtin_amdgcn_s_sleep(8);
                if (++it > WDOG) break;
            }
        }
        if (bid == 0) {
            for (int i = 0; i < 16; ++i)
                __hip_atomic_store(tpat + i * 16, 0xC0FFEE00u + (unsigned)i,
                                   __ATOMIC_RELAXED, __HIP_MEMORY_SCOPE_SYSTEM);
            asm volatile("s_waitcnt vmcnt(0)" ::: "memory");
            __hip_atomic_fetch_add(trdy, 1u, __ATOMIC_RELAXED, __HIP_MEMORY_SCOPE_AGENT);
        }
        if (bid == 1) {
            int it = 0;
            while (__hip_atomic_fetch_add(trdy, 0u, __ATOMIC_RELAXED, __HIP_MEMORY_SCOPE_AGENT) < 1u) {
                __builtin_amdgcn_s_sleep(8);
                if (++it > WDOG) break;
            }
            unsigned ok = 1u;
            for (int i = 0; i < 16; ++i)
                if (__hip_atomic_load(tpat + i * 16, __ATOMIC_RELAXED, __HIP_MEMORY_SCOPE_SYSTEM)
                    != 0xC0FFEE00u + (unsigned)i) ok = 0u;
            __hip_atomic_fetch_add(modep, 2u | (ok ? 0u : 1u), __ATOMIC_RELAXED, __HIP_MEMORY_SCOPE_AGENT);
        }
        unsigned mv; int spins = 0;
        while ((mv = __hip_atomic_fetch_add(modep, 0u, __ATOMIC_RELAXED, __HIP_MEMORY_SCOPE_AGENT)) < 2u) {
            __builtin_amdgcn_s_sleep(16);
            if (++spins > (1 << 22)) { mv = 3u; break; }   // timeout -> safe mode
        }
        ((unsigned*)hstage)[1] = mv & 1u;
    }
    __syncthreads();
    const unsigned needRel = ((unsigned*)hstage)[1];
    __syncthreads();

    // ---- startup phase 2: behavioral co-location probe (wave 0) ----
    // Iterations-to-see-all-32-tokens via sc0 loads: same-XCD (dirty-L2
    // delivery) ~1-2; cross-XCD (eviction ~10us) >=30 -> fail -> fallback.
    if (tid < 64) {
        unsigned seen = (lam < 32) ? 0u : 1u;
        unsigned expv = 0x5EED0000u + (unsigned)(lam * 8 + gid);
        int it = 0, done_at = 1 << 30;
        for (;;) {
            if (!seen && lam < 32) {
                unsigned v = __hip_atomic_load(flags + (size_t)(lam * 8 + gid) * 32 + 2,
                                               __ATOMIC_RELAXED, __HIP_MEMORY_SCOPE_AGENT);
                if (v == expv) seen = 1u;
            }
            ++it;
            if (__all((int)seen)) { done_at = it; break; }
            if (it >= 64) break;
        }
        unsigned ok = (done_at <= 12) ? 1u : 0u;
        if (lam == 0)
            __hip_atomic_fetch_add(gvote + (size_t)gid * 32, 0x10000u | ok,
                                   __ATOMIC_RELAXED, __HIP_MEMORY_SCOPE_AGENT);
    }
    __syncthreads();
    if (tid == 0) {
        unsigned gv = 0u; int sp2 = 0;
        for (;;) {
            gv = __hip_atomic_fetch_add(gvote + (size_t)gid * 32, 0u,
                                        __ATOMIC_RELAXED, __HIP_MEMORY_SCOPE_AGENT);
            if ((gv >> 16) >= 32u) break;
            __builtin_amdgcn_s_sleep(8);
            if (++sp2 > (1 << 20)) { gv = 0u; break; }
        }
        ((unsigned*)hstage)[0] = (((gv >> 16) >= 32u) && ((gv & 0xFFFFu) == 32u)) ? 1u : 0u;
    }
    __syncthreads();
    const unsigned fastgrp = ((unsigned*)hstage)[0];
    unsigned       fastE1  = fastgrp;   // fallback sync-wave demotion flag
    __syncthreads();

    f16* h0ring = (f16*)(ws + H0R_OFF);
    f16* h1ring = (f16*)(ws + H1R_OFF);
    const float* bias = (const float*)(ws + (layer ? BIAS1_OFF : BIAS0_OFF));
    const f16*   wimg = (const f16*)(ws + (layer ? W1I_OFF : W0I_OFF))
                      + (size_t)ht * (layer ? L1_IMG_HALVES : L0_IMG_HALVES);

    {
        const int n16 = KCx * 4 * 64;
        const uint4* src = (const uint4*)wimg;
        uint4* dst = (uint4*)sW;
        for (int i = tid; i < n16; i += 320) dst[i] = src[i];
    }
    __syncthreads();

    const float bi_i = bias[0 * NH + h0c + col];
    const float bi_f = bias[1 * NH + h0c + col];
    const float bi_g = bias[2 * NH + h0c + col];
    const float bi_o = bias[3 * NH + h0c + col];

    float cst[4];
#pragma unroll
    for (int r = 0; r < 4; ++r) cst[r] = 0.f;

    const f16x8* sBf = (const f16x8*)sW;
    const int rA   = b0 + (w & 3) * 16 + col;
    const int rofs = rA * 16 + (quad & 1) * 8;
    const int hq   = (quad >> 1) * 4096;

    unsigned long long pr0 = 0, pr1 = 0, pr2 = 0, pr3 = 0;   // deferred sys copy (fast L0 w3)
    unsigned useRmw = 0u;                                    // per-wave detect demotion
    unsigned vflag  = 0u;                                    // per-lane cached flag value

    if (w == 4 && lam == 0) {
        if (layer == 1) spin_cnt<4>(cntp(gid - 4, 0), 32u);   // L0 done step 0
        __hip_atomic_store(&go[0], 1u, __ATOMIC_RELAXED, __HIP_MEMORY_SCOPE_WORKGROUP);
    }

    for (int s = 0; s < NT; ++s) {
        const unsigned us = (unsigned)s;

        f32x4 ai = {0.f,0.f,0.f,0.f}, af = {0.f,0.f,0.f,0.f};
        f32x4 ag = {0.f,0.f,0.f,0.f}, ao = {0.f,0.f,0.f,0.f};

        if (w == 4) {
            // ===== SYNC WAVE =====
            if (!fastgrp) {
                // fallback: R14 relay (detect + go1)
                if (s > 0) {
                    if (fastE1) {
                        int it = 0;
                        for (;;) {
                            unsigned v = 0xFFFFFFFFu;
                            if (lam < 32)
                                v = __hip_atomic_load(flags + (size_t)(lam * 8 + gid) * 32,
                                                      __ATOMIC_RELAXED, __HIP_MEMORY_SCOPE_AGENT);
                            if (__all((int)(v >= us))) break;
                            if (++it > 20000) { fastE1 = 0u; break; }
                        }
                    }
                    if (!fastE1) {
                        int it = 0;
                        for (;;) {
                            unsigned v = 0xFFFFFFFFu;
                            if (lam < 32)
                                v = __hip_atomic_fetch_add(flags + (size_t)(lam * 8 + gid) * 32, 0u,
                                                           __ATOMIC_RELAXED, __HIP_MEMORY_SCOPE_AGENT);
                            if (__all((int)(v >= us))) break;
                            __builtin_amdgcn_s_sleep(2);
                            if (++it > WDOG) break;
                        }
                    }
                }
                if (lam == 0)
                    __hip_atomic_store(&go[1], us + 1u, __ATOMIC_RELAXED, __HIP_MEMORY_SCOPE_WORKGROUP);
            }
            // slack edge for s+1 (both modes; off the critical path)
            if (lam == 0 && s + 1 < NT) {
                const unsigned t = us + 1u;
                if (layer == 0) {
                    if (t >= (unsigned)RING)
                        spin_cnt<8>(cntp(gid + 4, (int)(t & 15u)), 32u * (t >> 4));
                } else {
                    spin_cnt<4>(cntp(gid - 4, (int)(t & 15u)), 32u * ((t >> 4) + 1u));
                }
                __hip_atomic_store(&go[0], t + 1u, __ATOMIC_RELAXED, __HIP_MEMORY_SCOPE_WORKGROUP);
            }
        } else {
            // ===== COMPUTE WAVES =====
            if (layer == 0) {
                if (fastgrp && w == 3 && s > 0) {   // issue deferred sys copy of s-1
                    unsigned long long* d = (unsigned long long*)
                        ((char*)h0ring + ((size_t)((s - 1) & 15) * SLOT_F16 + (size_t)ht * 4096
                                          + (size_t)b0 * 16) * 2) + (size_t)lam * 4;
                    st8_sys(d + 0, pr0); st8_sys(d + 1, pr1);
                    st8_sys(d + 2, pr2); st8_sys(d + 3, pr3);
                }
                const float* xr = xin + (size_t)rA * (NT * NDIN) + (size_t)s * NDIN + quad * 8;
#pragma unroll
                for (int j = 0; j < 2; ++j) {
                    float4 f0 = *(const float4*)(xr + j * 32);
                    float4 f1 = *(const float4*)(xr + j * 32 + 4);
                    f16x8 a;
                    a[0] = (f16)f0.x; a[1] = (f16)f0.y; a[2] = (f16)f0.z; a[3] = (f16)f0.w;
                    a[4] = (f16)f1.x; a[5] = (f16)f1.y; a[6] = (f16)f1.z; a[7] = (f16)f1.w;
                    ai = MFMA16(a, sBf[(0 * L0_KC + j) * 64 + lam], ai);
                    af = MFMA16(a, sBf[(1 * L0_KC + j) * 64 + lam], af);
                    ag = MFMA16(a, sBf[(2 * L0_KC + j) * 64 + lam], ag);
                    ao = MFMA16(a, sBf[(3 * L0_KC + j) * 64 + lam], ao);
                }
                // WAR gate (slack; sleepy, bounded)
                {
                    int it = 0;
                    while (__hip_atomic_load(&go[0], __ATOMIC_RELAXED, __HIP_MEMORY_SCOPE_WORKGROUP) <= us) {
                        __builtin_amdgcn_s_sleep(1);
                        if (++it > WDOG) break;
                    }
                }
            } else {
                {
                    int it = 0;
                    while (__hip_atomic_load(&go[0], __ATOMIC_RELAXED, __HIP_MEMORY_SCOPE_WORKGROUP) <= us) {
                        __builtin_amdgcn_s_sleep(1);
                        if (++it > WDOG) break;
                    }
                }
                const f16* hp0 = h0ring + (size_t)(s & 15) * SLOT_F16;
#pragma unroll
                for (int j = 0; j < 16; ++j) {
                    f16x8 a = *(const f16x8*)(hp0 + (size_t)(2 * j) * 4096 + hq + rofs);
                    ai = MFMA16(a, sBf[(0 * L1_KC + j) * 64 + lam], ai);
                    af = MFMA16(a, sBf[(1 * L1_KC + j) * 64 + lam], af);
                    ag = MFMA16(a, sBf[(2 * L1_KC + j) * 64 + lam], ag);
                    ao = MFMA16(a, sBf[(3 * L1_KC + j) * 64 + lam], ao);
                }
            }

            // ---- own edge ----
            if (fastgrp) {
                // SELF-DETECT: lanes 0-31 poll the group's 32 flag lines (sc0),
                // sleepy spin; demote to RMW freshness; watchdog-bounded.
                if (s > 0) {
                    if (lam >= 32) vflag = 0xFFFFFFFFu;
                    int it = 0;
                    for (;;) {
                        if (lam < 32 && vflag < us) {
                            if (!useRmw)
                                vflag = __hip_atomic_load(flags + (size_t)(lam * 8 + gid) * 32,
                                                          __ATOMIC_RELAXED, __HIP_MEMORY_SCOPE_AGENT);
                            else
                                vflag = __hip_atomic_fetch_add(flags + (size_t)(lam * 8 + gid) * 32, 0u,
                                                               __ATOMIC_RELAXED, __HIP_MEMORY_SCOPE_AGENT);
                        }
                        if (__all((int)(vflag >= us))) break;
                        if (++it > 20000) useRmw = 1u;   // safety: RMW freshness
                        if (it > WDOG) break;            // watchdog
                        __builtin_amdgcn_s_sleep(1);
                    }
                }
            } else {
                int it = 0;
                while (__hip_atomic_load(&go[1], __ATOMIC_RELAXED, __HIP_MEMORY_SCOPE_WORKGROUP) <= us) {
                    __builtin_amdgcn_s_sleep(1);
                    if (++it > WDOG) break;
                }
            }

            // ---- own-dependent 16 KC ----
            {
                const f16* hpo = (layer ? h1ring : h0ring) + (size_t)((s + RING - 1) & 15) * SLOT_F16;
                const int  wb  = layer ? 16 : 2;
#pragma unroll
                for (int j = 0; j < 16; ++j) {
                    f16x8 a = *(const f16x8*)(hpo + (size_t)(2 * j) * 4096 + hq + rofs);
                    ai = MFMA16(a, sBf[(0 * KCx + wb + j) * 64 + lam], ai);
                    af = MFMA16(a, sBf[(1 * KCx + wb + j) * 64 + lam], af);
                    ag = MFMA16(a, sBf[(2 * KCx + wb + j) * 64 + lam], ag);
                    ao = MFMA16(a, sBf[(3 * KCx + wb + j) * 64 + lam], ao);
                }
            }

            // ---- cell update (wave-local), stage h into LDS ----
#pragma unroll
            for (int r = 0; r < 4; ++r) {
                float iv = ai[r] + bi_i;
                float fv = af[r] + bi_f;
                float gv = ag[r] + bi_g;
                float ov = ao[r] + bi_o;
                float cc = sigf(fv) * cst[r] + sigf(iv) * tanhx(gv);
                cst[r] = cc;
                float hh = sigf(ov) * tanhx(cc);
                hstage[((w & 3) * 16 + quad * 4 + r) * 16 + col] = (f16)hh;
            }

            // deferred drain + cnt bump for s-1 (fast L0 w3): stores had the
            // whole GEMM to complete -> vmcnt(0) is ~free here.
            if (fastgrp && layer == 0 && w == 3 && s > 0) {
                asm volatile("s_waitcnt vmcnt(0)" ::: "memory");
                if (lam == 0) {
                    if (needRel)
                        __hip_atomic_fetch_add(cntp(gid, (s - 1) & 15), 1u, __ATOMIC_RELEASE, __HIP_MEMORY_SCOPE_AGENT);
                    else
                        __hip_atomic_fetch_add(cntp(gid, (s - 1) & 15), 1u, __ATOMIC_RELAXED, __HIP_MEMORY_SCOPE_AGENT);
                }
            }
        }

        __syncthreads();   // T: hstage complete; all A-loads consumed

        // ring write: fast = one plain 16B write-back store (dirty L2);
        // fallback = 2x8B system write-through
        if (tid < 128) {
            f16* dstf = (layer ? h1ring : h0ring)
                      + (size_t)(s & 15) * SLOT_F16 + (size_t)ht * 4096
                      + (size_t)b0 * 16 + (size_t)tid * 8;
            if (fastgrp) {
                *(uint4*)dstf = ((const uint4*)hstage)[tid];
            } else {
                const unsigned long long* sp = (const unsigned long long*)hstage;
                st8_sys((unsigned long long*)dstf, sp[tid * 2]);
                st8_sys((unsigned long long*)dstf + 1, sp[tid * 2 + 1]);
            }
        }
        // wave 3 captures hstage for next step's deferred sys copy (fast L0)
        if (fastgrp && layer == 0 && w == 3) {
            const unsigned long long* sp = (const unsigned long long*)hstage;
            pr0 = sp[lam * 4 + 0]; pr1 = sp[lam * 4 + 1];
            pr2 = sp[lam * 4 + 2]; pr3 = sp[lam * 4 + 3];
        }

        // staleness bound: one aligned acquire-inv per RING steps
        if (tid == 128 && ((s & 15) == 15))
            (void)__hip_atomic_load((unsigned*)(ws + BAR_OFF), __ATOMIC_ACQUIRE, __HIP_MEMORY_SCOPE_AGENT);

        __syncthreads();   // B4: ring stores drained (L2 fast / LLC fallback)

        if (tid == 192) {  // publisher (wave 3 lane 0)
            if (fastgrp) {
                __hip_atomic_store(flags + (size_t)bid * 32, us + 1u,
                                   __ATOMIC_RELAXED, __HIP_MEMORY_SCOPE_AGENT);
                if (layer == 1)   // cnt for WAR consumers (RMW lands at LLC)
                    __hip_atomic_fetch_add(cntp(gid, s & 15), 1u, __ATOMIC_RELAXED, __HIP_MEMORY_SCOPE_AGENT);
                // fast L0: cnt deferred to next step (post sys-copy drain)
            } else {
                if (needRel)
                    __hip_atomic_fetch_add(cntp(gid, s & 15), 1u, __ATOMIC_RELEASE, __HIP_MEMORY_SCOPE_AGENT);
                else
                    __hip_atomic_fetch_add(cntp(gid, s & 15), 1u, __ATOMIC_RELAXED, __HIP_MEMORY_SCOPE_AGENT);
                __hip_atomic_fetch_add(flags + (size_t)bid * 32, 1u,
                                       __ATOMIC_RELAXED, __HIP_MEMORY_SCOPE_AGENT);
            }
        }
    }

    // epilogue: fast-L0 deferred sys copy + cnt for step 511 (slot 15)
    if (fastgrp && layer == 0 && w == 3) {
        unsigned long long* d = (unsigned long long*)
            ((char*)h0ring + ((size_t)15 * SLOT_F16 + (size_t)ht * 4096
                              + (size_t)b0 * 16) * 2) + (size_t)lam * 4;
        st8_sys(d + 0, pr0); st8_sys(d + 1, pr1);
        st8_sys(d + 2, pr2); st8_sys(d + 3, pr3);
        asm volatile("s_waitcnt vmcnt(0)" ::: "memory");
        if (lam == 0) {
            if (needRel)
                __hip_atomic_fetch_add(cntp(gid, 15), 1u, __ATOMIC_RELEASE, __HIP_MEMORY_SCOPE_AGENT);
            else
                __hip_atomic_fetch_add(cntp(gid, 15), 1u, __ATOMIC_RELAXED, __HIP_MEMORY_SCOPE_AGENT);
        }
    }

    // L1 blocks: final RELEASE (wbl2 flushes agent-dirty h1 to LLC for the FC)
    if (layer == 1 && tid == 0)
        __hip_atomic_fetch_add(finp, 1u, __ATOMIC_RELEASE, __HIP_MEMORY_SCOPE_AGENT);

    if (bid == 0) {
        if (tid == 0) {
            int it = 0;
            while (__hip_atomic_fetch_add(finp, 0u, __ATOMIC_RELAXED, __HIP_MEMORY_SCOPE_AGENT) < 128u) {
                __builtin_amdgcn_s_sleep(8);
                if (++it > (1 << 22)) break;
            }
            (void)__hip_atomic_load((unsigned*)(ws + BAR_OFF), __ATOMIC_ACQUIRE, __HIP_MEMORY_SCOPE_AGENT);
        }
        __syncthreads();
        if (tid < 256) {
            const f16* hrow = h1ring + (size_t)15 * SLOT_F16 + (size_t)tid * 16;  // slot 511&15
            float acc = fcb[0];
#pragma unroll 4
            for (int t2 = 0; t2 < 32; ++t2) {
                f16x8 a = *(const f16x8*)(hrow + t2 * 4096);
                f16x8 b = *(const f16x8*)(hrow + t2 * 4096 + 8);
#pragma unroll
                for (int e = 0; e < 8; ++e)
                    acc += fcW[t2 * 16 + e] * (float)a[e] + fcW[t2 * 16 + 8 + e] * (float)b[e];
            }
            out[tid] = acc;
        }
    }
}

// ---------------------------------------------------------------------------
extern "C" void kernel_launch(void* const* d_in, const int* in_sizes, int n_in,
                              void* d_out, int out_size, void* d_ws, size_t ws_size,
                              hipStream_t stream) {
    const float* x    = (const float*)d_in[0];
    const float* Wih0 = (const float*)d_in[1];
    const float* Whh0 = (const float*)d_in[2];
    const float* bih0 = (const float*)d_in[3];
    const float* bhh0 = (const float*)d_in[4];
    const float* Wih1 = (const float*)d_in[5];
    const float* Whh1 = (const float*)d_in[6];
    const float* bih1 = (const float*)d_in[7];
    const float* bhh1 = (const float*)d_in[8];
    const float* fcW  = (const float*)d_in[9];
    const float* fcb  = (const float*)d_in[10];
    char*  ws  = (char*)d_ws;
    float* out = (float*)d_out;

    if (ws_size < WS_NEED) {
        hipMemsetAsync(d_out, 0, (size_t)out_size * sizeof(float), stream);
        return;
    }

    hipFuncSetAttribute(reinterpret_cast<const void*>(lstm_persist),
                        hipFuncAttributeMaxDynamicSharedMemorySize, LDS_SIZE);

    prep_weights<<<1600, 256, 0, stream>>>(Wih0, Whh0, Wih1, Whh1, ws);
    prep_state<<<1100, 256, 0, stream>>>(bih0, bhh0, bih1, bhh1, ws);
    lstm_persist<<<256, 320, LDS_SIZE, stream>>>(ws, x, fcW, fcb, out);
}